// Round 1
// baseline (1685.681 us; speedup 1.0000x reference)
//
#include <hip/hip_runtime.h>
#include <math.h>

// ---------------------------------------------------------------------------
// Net_37512244363273: 5-level edge-conditioned graph conv + voxel pooling + FC
// Output: [8,10] log_softmax logits (80 floats) + closs scalar = 81 floats.
// ---------------------------------------------------------------------------

#define DEVINL __device__ __forceinline__

// Monotone float -> uint encoding for atomicMax-based segment max.
// Property: a < b  <=>  enc(a) < enc(b). enc(x) >= 0x007FFFFF for all reals
// (enc(-inf) = 0x007FFFFF), so a zero-initialized buffer means "empty".
DEVINL unsigned enc_f(float f) {
    unsigned u = __float_as_uint(f);
    return (u & 0x80000000u) ? ~u : (u | 0x80000000u);
}
DEVINL float dec_f(unsigned u) {
    return (u & 0x80000000u) ? __uint_as_float(u & 0x7FFFFFFFu)
                             : __uint_as_float(~u);
}

// ---------------------------------------------------------------------------
// conv_edge_k: one thread per edge.
//   h  = tanh(eattr @ w1 + b1)            [5]
//   We = h @ w2 + b2                      [CI,CO]  (computed on the fly)
//   msg= x[src] . We                      [CO]
//   atomicAdd into s[dst], cnt[dst]; wave-reduced Sum(We^2) -> sq.
// o-loop fully unrolled so msg[] stays in VGPRs; i-loop dynamic (bounded code).
// ---------------------------------------------------------------------------
template<int CI, int CO>
__global__ __launch_bounds__(256) void conv_edge_k(
    int E,
    const int*   __restrict__ src, const int* __restrict__ dst,
    const float* __restrict__ eattr,
    const float* __restrict__ w1,  const float* __restrict__ b1,
    const float* __restrict__ w2,  const float* __restrict__ b2,
    const float* __restrict__ x,           // [N, CI]
    float* __restrict__ s,                 // [N, CO] zero-init
    float* __restrict__ cnt,               // [N]     zero-init
    float* __restrict__ sq)                // [1]     zero-init
{
    constexpr int CICO = CI * CO;
    __shared__ float w1s[15], b1s[5];
    __shared__ float w2s[5 * CICO], b2s[CICO];
    for (int t = threadIdx.x; t < 5 * CICO; t += 256) w2s[t] = w2[t];
    for (int t = threadIdx.x; t < CICO;     t += 256) b2s[t] = b2[t];
    if (threadIdx.x < 15) w1s[threadIdx.x] = w1[threadIdx.x];
    if (threadIdx.x < 5)  b1s[threadIdx.x] = b1[threadIdx.x];
    __syncthreads();

    int e = blockIdx.x * 256 + threadIdx.x;
    float sqv = 0.f;
    if (e < E) {
        float ea0 = eattr[e * 3 + 0], ea1 = eattr[e * 3 + 1], ea2 = eattr[e * 3 + 2];
        float h[5];
        #pragma unroll
        for (int k = 0; k < 5; k++)
            h[k] = tanhf(ea0 * w1s[k] + ea1 * w1s[5 + k] + ea2 * w1s[10 + k] + b1s[k]);

        int sv = src[e], dv = dst[e];
        float msg[CO];
        #pragma unroll
        for (int o = 0; o < CO; o++) msg[o] = 0.f;

        for (int i = 0; i < CI; i++) {
            float xi = x[sv * CI + i];
            const float* b2p = &b2s[i * CO];
            const float* w2p = &w2s[i * CO];
            #pragma unroll
            for (int o = 0; o < CO; o++) {
                float we = b2p[o];
                #pragma unroll
                for (int k = 0; k < 5; k++) we += h[k] * w2p[k * CICO + o];
                sqv    += we * we;
                msg[o] += xi * we;
            }
        }
        float* sp = &s[dv * CO];
        #pragma unroll
        for (int o = 0; o < CO; o++) atomicAdd(&sp[o], msg[o]);
        atomicAdd(&cnt[dv], 1.0f);
    }
    // wave64 reduction of sqv, one atomic per wave
    #pragma unroll
    for (int off = 32; off; off >>= 1) sqv += __shfl_down(sqv, off);
    if ((threadIdx.x & 63) == 0) atomicAdd(sq, sqv);
}

// ---------------------------------------------------------------------------
// node_pool_k: one thread per node.
//   out = s/max(cnt,1) + x@root + bias    [CO]
//   pool scatter: encoded atomicMax(out) into xm[cluster],
//                 atomicAdd pos into ps[cluster], cntc[cluster]++.
// (conv output y is never materialized in global memory.)
// ---------------------------------------------------------------------------
template<int CI, int CO>
__global__ __launch_bounds__(256) void node_pool_k(
    int N,
    const float* __restrict__ s, const float* __restrict__ cnt,
    const float* __restrict__ x,           // [N, CI]
    const float* __restrict__ root,        // [CI, CO]
    const float* __restrict__ bias,        // [CO]
    const int*   __restrict__ cluster,     // [N]
    const float* __restrict__ pos,         // [N, 3]
    unsigned* __restrict__ xm,             // [NN, CO] zero-init (encoded max)
    float* __restrict__ ps,                // [NN, 3]  zero-init
    float* __restrict__ cntc)              // [NN]     zero-init
{
    constexpr int CICO = CI * CO;
    __shared__ float roots[CICO], biass[CO];
    for (int t = threadIdx.x; t < CICO; t += 256) roots[t] = root[t];
    for (int t = threadIdx.x; t < CO;   t += 256) biass[t] = bias[t];
    __syncthreads();

    int v = blockIdx.x * 256 + threadIdx.x;
    if (v >= N) return;

    float c = cnt[v]; c = c > 1.f ? c : 1.f;
    float inv = 1.f / c;
    float out[CO];
    #pragma unroll
    for (int o = 0; o < CO; o++) out[o] = s[v * CO + o] * inv + biass[o];
    for (int i = 0; i < CI; i++) {
        float xi = x[v * CI + i];
        #pragma unroll
        for (int o = 0; o < CO; o++) out[o] += xi * roots[i * CO + o];
    }
    int cl = cluster[v];
    unsigned* xp = &xm[cl * CO];
    #pragma unroll
    for (int o = 0; o < CO; o++) atomicMax(&xp[o], enc_f(out[o]));
    atomicAdd(&ps[cl * 3 + 0], pos[v * 3 + 0]);
    atomicAdd(&ps[cl * 3 + 1], pos[v * 3 + 1]);
    atomicAdd(&ps[cl * 3 + 2], pos[v * 3 + 2]);
    atomicAdd(&cntc[cl], 1.0f);
}

// ---------------------------------------------------------------------------
// pool_fin_k: one thread per cluster. Decode max (empty -> 0), mean pos,
// write x_{l+1} = [xm, pm] and pos_{l+1} = pm.
// ---------------------------------------------------------------------------
template<int CO>
__global__ __launch_bounds__(256) void pool_fin_k(
    int NN,
    const unsigned* __restrict__ xm, const float* __restrict__ ps,
    const float* __restrict__ cntc,
    float* __restrict__ xn,                // [NN, CO+3]
    float* __restrict__ pn)                // [NN, 3]
{
    int c = blockIdx.x * 256 + threadIdx.x;
    if (c >= NN) return;
    float n = cntc[c]; n = n > 1.f ? n : 1.f;
    float inv = 1.f / n;
    float pm0 = ps[c * 3 + 0] * inv, pm1 = ps[c * 3 + 1] * inv, pm2 = ps[c * 3 + 2] * inv;
    #pragma unroll
    for (int o = 0; o < CO; o++) {
        unsigned u = xm[c * CO + o];
        float f = (u == 0u) ? 0.f : dec_f(u);
        if (!isfinite(f)) f = 0.f;
        xn[c * (CO + 3) + o] = f;
    }
    xn[c * (CO + 3) + CO + 0] = pm0;
    xn[c * (CO + 3) + CO + 1] = pm1;
    xn[c * (CO + 3) + CO + 2] = pm2;
    pn[c * 3 + 0] = pm0; pn[c * 3 + 1] = pm1; pn[c * 3 + 2] = pm2;
}

// ---------------------------------------------------------------------------
// fc_k: single block. feat = x5.reshape(8,376); logits = feat@fc_w + fc_b;
// log_softmax per row; closs = sum_l sq[l] / (E_l*ci_l*co_l).
// ---------------------------------------------------------------------------
__global__ __launch_bounds__(128) void fc_k(
    const float* __restrict__ x5,          // [64, 47] == [8, 376]
    const float* __restrict__ fc_w,        // [376, 10]
    const float* __restrict__ fc_b,        // [10]
    const float* __restrict__ sq,          // [5]
    float* __restrict__ out)               // [81]
{
    __shared__ float feat[8 * 376];
    __shared__ float logit[80];
    __shared__ float roff[8];
    for (int t = threadIdx.x; t < 8 * 376; t += 128) feat[t] = x5[t];
    __syncthreads();
    int t = threadIdx.x;
    if (t < 80) {
        int b = t / 10, j = t % 10;
        float acc = fc_b[j];
        for (int k = 0; k < 376; k++) acc += feat[b * 376 + k] * fc_w[k * 10 + j];
        logit[t] = acc;
    }
    __syncthreads();
    if (t < 8) {
        float m = -1e30f;
        for (int j = 0; j < 10; j++) m = fmaxf(m, logit[t * 10 + j]);
        float ssum = 0.f;
        for (int j = 0; j < 10; j++) ssum += expf(logit[t * 10 + j] - m);
        roff[t] = m + logf(ssum);
    }
    __syncthreads();
    if (t < 80) out[t] = logit[t] - roff[t / 10];
    if (t == 0) {
        float closs = 0.f;
        closs += sq[0] * (1.0f / 12582912.0f);   // 1048576 * 1  * 12
        closs += sq[1] * (1.0f / 78643200.0f);   // 262144  * 15 * 20
        closs += sq[2] * (1.0f / 42205184.0f);   // 65536   * 23 * 28
        closs += sq[3] * (1.0f / 18284544.0f);   // 16384   * 31 * 36
        closs += sq[4] * (1.0f / 7028736.0f);    // 4096    * 39 * 44
        out[80] = closs;
    }
}

// ---------------------------------------------------------------------------

extern "C" void kernel_launch(void* const* d_in, const int* in_sizes, int n_in,
                              void* d_out, int out_size, void* d_ws, size_t ws_size,
                              hipStream_t stream)
{
    static const int NSa[6] = {65536, 16384, 4096, 1024, 256, 64};
    static const int ESa[5] = {1048576, 262144, 65536, 16384, 4096};
    static const int COa[5] = {12, 20, 28, 36, 44};

    const float* x0   = (const float*)d_in[0];
    const float* pos0 = (const float*)d_in[1];

    // -------- workspace layout (floats), 256 B-aligned chunks --------
    float* ws = (float*)d_ws;
    size_t off = 0;
    auto alloc = [&](size_t n) -> float* {
        float* p = ws + off;
        off += (n + 63) & ~(size_t)63;
        return p;
    };
    float* s[5]; float* cnt[5]; unsigned* xm[5]; float* ps[5]; float* cntc[5];
    float* xn[5]; float* pn[5];
    for (int l = 0; l < 5; l++) {
        s[l]    = alloc((size_t)NSa[l] * COa[l]);
        cnt[l]  = alloc((size_t)NSa[l]);
        xm[l]   = (unsigned*)alloc((size_t)NSa[l + 1] * COa[l]);
        ps[l]   = alloc((size_t)NSa[l + 1] * 3);
        cntc[l] = alloc((size_t)NSa[l + 1]);
        xn[l]   = alloc((size_t)NSa[l + 1] * (COa[l] + 3));
        pn[l]   = alloc((size_t)NSa[l + 1] * 3);
    }
    float* sq = alloc(8);
    size_t total_bytes = off * sizeof(float);

    // Single zero-init covers all accumulators (xm's encoding treats 0 as
    // "below -inf", so zero == empty for the max buffers too).
    hipMemsetAsync(d_ws, 0, total_bytes, stream);

#define LVL(l, CI_, CO_) do {                                                  \
    const int*   srcp = (const int*)  d_in[2  + 10 * (l)];                     \
    const int*   dstp = (const int*)  d_in[3  + 10 * (l)];                     \
    const float* ea   = (const float*)d_in[4  + 10 * (l)];                     \
    const int*   clus = (const int*)  d_in[5  + 10 * (l)];                     \
    const float* w1p  = (const float*)d_in[6  + 10 * (l)];                     \
    const float* b1p  = (const float*)d_in[7  + 10 * (l)];                     \
    const float* w2p  = (const float*)d_in[8  + 10 * (l)];                     \
    const float* b2p  = (const float*)d_in[9  + 10 * (l)];                     \
    const float* rtp  = (const float*)d_in[10 + 10 * (l)];                     \
    const float* bsp  = (const float*)d_in[11 + 10 * (l)];                     \
    const float* xin   = ((l) == 0) ? x0   : xn[(l) - 1 < 0 ? 0 : (l) - 1];    \
    const float* posin = ((l) == 0) ? pos0 : pn[(l) - 1 < 0 ? 0 : (l) - 1];    \
    int E = ESa[(l)], N = NSa[(l)], NN = NSa[(l) + 1];                         \
    conv_edge_k<CI_, CO_><<<(E + 255) / 256, 256, 0, stream>>>(                \
        E, srcp, dstp, ea, w1p, b1p, w2p, b2p, xin, s[(l)], cnt[(l)],          \
        sq + (l));                                                             \
    node_pool_k<CI_, CO_><<<(N + 255) / 256, 256, 0, stream>>>(                \
        N, s[(l)], cnt[(l)], xin, rtp, bsp, clus, posin, xm[(l)], ps[(l)],     \
        cntc[(l)]);                                                            \
    pool_fin_k<CO_><<<(NN + 255) / 256, 256, 0, stream>>>(                     \
        NN, xm[(l)], ps[(l)], cntc[(l)], xn[(l)], pn[(l)]);                    \
} while (0)

    LVL(0, 1, 12);
    LVL(1, 15, 20);
    LVL(2, 23, 28);
    LVL(3, 31, 36);
    LVL(4, 39, 44);
#undef LVL

    fc_k<<<1, 128, 0, stream>>>(xn[4], (const float*)d_in[52],
                                (const float*)d_in[53], sq, (float*)d_out);
}

// Round 4
// 1247.320 us; speedup vs baseline: 1.3514x; 1.3514x over previous
//
#include <hip/hip_runtime.h>
#include <math.h>

// ---------------------------------------------------------------------------
// Net_37512244363273: 5-level edge-conditioned graph conv + voxel pooling + FC
// Round 4: fixes the scan_all_k OOB (rounds 2-3 scanned histogram arrays with
// the index-array length, not the bin count -> 4 MB OOB write -> GPU fault).
// Design: counting-sort CSR (edges by dst, nodes by cluster), conv fused into
// node-side gather (no E*CO msg buffer), zero float atomics (round 1 showed
// 426 MB device-scope atomic write traffic = 757 us on L0 alone).
// Workspace ~11.8 MB. Output: [8,10] log_softmax (80) + closs = 81 floats.
// ---------------------------------------------------------------------------

// ---- segment descriptor for the 10 CSR builds (5 edge-dst + 5 cluster) ----
struct SegArgs {
    const int* idx[10];   // dst arrays (seg 0-4), cluster arrays (seg 5-9)
    int*       cnt[10];   // histogram (nb bins, zero-init; destroyed by scatter)
    int*       rp [10];   // exclusive scan out, nb+1 entries (rp[nb] = total)
    int*       out[10];   // CSR payload: eid / cnid (source index)
    int        n  [10];   // number of index elements (edges / nodes)
    int        nb [10];   // number of histogram bins  (nodes / clusters)
};

__global__ __launch_bounds__(256) void hist_all_k(SegArgs a, int total) {
    int t = blockIdx.x * 256 + threadIdx.x;
    if (t >= total) return;
    int start = 0;
    for (int s = 0; s < 10; s++) {
        if (t < start + a.n[s]) {
            atomicAdd(&a.cnt[s][a.idx[s][t - start]], 1);
            return;
        }
        start += a.n[s];
    }
}

// one block per segment; chunked exclusive scan over nb bins (nb <= 65536)
__global__ __launch_bounds__(1024) void scan_all_k(SegArgs a) {
    int b = blockIdx.x;
    const int* in = a.cnt[b];
    int* out = a.rp[b];
    int nb = a.nb[b];                      // BIN count (the round-2/3 bug: used n)
    __shared__ int part[1024];
    int t = threadIdx.x;
    int chunk = (nb + 1023) >> 10;
    int lo = t * chunk; if (lo > nb) lo = nb;
    int hi = lo + chunk; if (hi > nb) hi = nb;
    int s = 0;
    for (int i = lo; i < hi; i++) s += in[i];
    part[t] = s;
    __syncthreads();
    for (int d = 1; d < 1024; d <<= 1) {
        int v = (t >= d) ? part[t - d] : 0;
        __syncthreads();
        part[t] += v;
        __syncthreads();
    }
    int run = part[t] - s;                 // exclusive prefix of this chunk
    for (int i = lo; i < hi; i++) { out[i] = run; run += in[i]; }
    if (t == 1023) out[nb] = run;          // total
}

// countdown-scatter: reuses cnt as cursor (slots filled in reverse; order
// within a segment is irrelevant for sum/mean/max). cnt is destroyed.
__global__ __launch_bounds__(256) void scatter_all_k(SegArgs a, int total) {
    int t = blockIdx.x * 256 + threadIdx.x;
    if (t >= total) return;
    int start = 0;
    for (int s = 0; s < 10; s++) {
        if (t < start + a.n[s]) {
            int i = t - start;
            int d = a.idx[s][i];
            int p = atomicSub(&a.cnt[s][d], 1) - 1;
            a.out[s][a.rp[s][d] + p] = i;
            return;
        }
        start += a.n[s];
    }
}

// ---------------------------------------------------------------------------
// node_conv_k: fused conv + gather. One thread per (node v, group g of OW
// channels). Walks v's CSR edge list; per edge recomputes h=tanh(ea@w1+b1)
// and the OW columns of We=h@w2+b2; accumulates x[src].We and Sum(We^2).
// Each edge has exactly one dst and each channel one group, so the sqv
// partials tile Sum(We^2) exactly. deg = rp[v+1]-rp[v].
// ---------------------------------------------------------------------------
template<int CI, int CO, int OW>
__global__ __launch_bounds__(256) void node_conv_k(
    int N,
    const int* __restrict__ rp, const int* __restrict__ eid,
    const int* __restrict__ src, const float* __restrict__ eattr,
    const float* __restrict__ w1, const float* __restrict__ b1,
    const float* __restrict__ w2, const float* __restrict__ b2,
    const float* __restrict__ root, const float* __restrict__ bias,
    const float* __restrict__ x,           // [N, CI]
    float* __restrict__ y,                 // [N, CO]
    float* __restrict__ sq)                // [1]  zero-init
{
    constexpr int G    = CO / OW;
    constexpr int CICO = CI * CO;
    __shared__ float w1s[15], b1s[5];
    __shared__ float w2s[5 * CICO], b2s[CICO], roots[CICO], biass[CO];
    for (int t = threadIdx.x; t < 5 * CICO; t += 256) w2s[t]   = w2[t];
    for (int t = threadIdx.x; t < CICO;     t += 256) b2s[t]   = b2[t];
    for (int t = threadIdx.x; t < CICO;     t += 256) roots[t] = root[t];
    for (int t = threadIdx.x; t < CO;       t += 256) biass[t] = bias[t];
    if (threadIdx.x < 15) w1s[threadIdx.x] = w1[threadIdx.x];
    if (threadIdx.x < 5)  b1s[threadIdx.x] = b1[threadIdx.x];
    __syncthreads();

    int t = blockIdx.x * 256 + threadIdx.x;
    float sqv = 0.f;
    if (t < N * G) {
        int v  = t / G;
        int ob = (t % G) * OW;
        int r0 = rp[v], r1 = rp[v + 1];
        int d  = r1 - r0;
        float acc[OW];
        #pragma unroll
        for (int oo = 0; oo < OW; oo++) acc[oo] = 0.f;

        for (int j = r0; j < r1; j++) {
            int e = eid[j];
            float ea0 = eattr[e * 3 + 0], ea1 = eattr[e * 3 + 1], ea2 = eattr[e * 3 + 2];
            float h[5];
            #pragma unroll
            for (int k = 0; k < 5; k++)
                h[k] = tanhf(ea0 * w1s[k] + ea1 * w1s[5 + k] + ea2 * w1s[10 + k] + b1s[k]);
            int sv = src[e];
            for (int i = 0; i < CI; i++) {
                float xi = x[sv * CI + i];
                #pragma unroll
                for (int oo = 0; oo < OW; oo++) {
                    int o = ob + oo;
                    float we = b2s[i * CO + o];
                    #pragma unroll
                    for (int k = 0; k < 5; k++) we += h[k] * w2s[k * CICO + i * CO + o];
                    sqv     += we * we;
                    acc[oo] += xi * we;
                }
            }
        }
        float inv = 1.f / fmaxf((float)d, 1.f);
        #pragma unroll
        for (int oo = 0; oo < OW; oo++) acc[oo] *= inv;
        for (int i = 0; i < CI; i++) {
            float xi = x[v * CI + i];
            #pragma unroll
            for (int oo = 0; oo < OW; oo++)
                acc[oo] += xi * roots[i * CO + ob + oo];
        }
        #pragma unroll
        for (int oo = 0; oo < OW; oo++)
            y[(size_t)v * CO + ob + oo] = acc[oo] + biass[ob + oo];
    }
    // wave64 reduction, one atomic per wave (no early return above this!)
    #pragma unroll
    for (int off = 32; off; off >>= 1) sqv += __shfl_down(sqv, off);
    if ((threadIdx.x & 63) == 0) atomicAdd(sq, sqv);
}

// ---------------------------------------------------------------------------
// pool_k: one thread per (cluster, channel). Gather-max features, gather-mean
// pos via cluster CSR. Empty cluster -> 0 (matches isfinite guard in ref).
// ---------------------------------------------------------------------------
template<int CO>
__global__ __launch_bounds__(256) void pool_k(
    int NN,
    const int* __restrict__ crp, const int* __restrict__ cnid,
    const float* __restrict__ y, const float* __restrict__ pos,
    float* __restrict__ xn,                // [NN, CO+3]
    float* __restrict__ pn)                // [NN, 3]
{
    int t = blockIdx.x * 256 + threadIdx.x;
    if (t >= NN * (CO + 3)) return;
    int c = t / (CO + 3), o = t % (CO + 3);
    int r0 = crp[c], r1 = crp[c + 1];
    int d = r1 - r0;
    if (o < CO) {
        float m = -INFINITY;
        for (int j = r0; j < r1; j++)
            m = fmaxf(m, y[(size_t)cnid[j] * CO + o]);
        if (d == 0 || !isfinite(m)) m = 0.f;
        xn[c * (CO + 3) + o] = m;
    } else {
        int k = o - CO;
        float sum = 0.f;
        for (int j = r0; j < r1; j++)
            sum += pos[cnid[j] * 3 + k];
        float pm = sum / fmaxf((float)d, 1.f);
        xn[c * (CO + 3) + CO + k] = pm;
        pn[c * 3 + k] = pm;
    }
}

// ---------------------------------------------------------------------------
// fc_k: single block. logits = feat@fc_w + fc_b; log_softmax; closs.
// ---------------------------------------------------------------------------
__global__ __launch_bounds__(128) void fc_k(
    const float* __restrict__ x5,          // [64,47] == [8,376]
    const float* __restrict__ fc_w, const float* __restrict__ fc_b,
    const float* __restrict__ sq, float* __restrict__ out)
{
    __shared__ float feat[8 * 376];
    __shared__ float logit[80];
    __shared__ float roff[8];
    for (int t = threadIdx.x; t < 8 * 376; t += 128) feat[t] = x5[t];
    __syncthreads();
    int t = threadIdx.x;
    if (t < 80) {
        int b = t / 10, j = t % 10;
        float acc = fc_b[j];
        for (int k = 0; k < 376; k++) acc += feat[b * 376 + k] * fc_w[k * 10 + j];
        logit[t] = acc;
    }
    __syncthreads();
    if (t < 8) {
        float m = -1e30f;
        for (int j = 0; j < 10; j++) m = fmaxf(m, logit[t * 10 + j]);
        float ssum = 0.f;
        for (int j = 0; j < 10; j++) ssum += expf(logit[t * 10 + j] - m);
        roff[t] = m + logf(ssum);
    }
    __syncthreads();
    if (t < 80) out[t] = logit[t] - roff[t / 10];
    if (t == 0) {
        float closs = 0.f;
        closs += sq[0] * (1.0f / 12582912.0f);   // 1048576 * 1  * 12
        closs += sq[1] * (1.0f / 78643200.0f);   // 262144  * 15 * 20
        closs += sq[2] * (1.0f / 42205184.0f);   // 65536   * 23 * 28
        closs += sq[3] * (1.0f / 18284544.0f);   // 16384   * 31 * 36
        closs += sq[4] * (1.0f / 7028736.0f);    // 4096    * 39 * 44
        out[80] = closs;
    }
}

// ---------------------------------------------------------------------------

extern "C" void kernel_launch(void* const* d_in, const int* in_sizes, int n_in,
                              void* d_out, int out_size, void* d_ws, size_t ws_size,
                              hipStream_t stream)
{
    static const int NSa[6] = {65536, 16384, 4096, 1024, 256, 64};
    static const int ESa[5] = {1048576, 262144, 65536, 16384, 4096};
    static const int COa[5] = {12, 20, 28, 36, 44};

    const float* x0   = (const float*)d_in[0];
    const float* pos0 = (const float*)d_in[1];

    // ---- workspace layout, 4-byte words, 256B-aligned chunks (~11.8 MB) ----
    int* wsw = (int*)d_ws;
    size_t off = 0;
    auto alw = [&](size_t n) -> size_t {
        size_t p = off; off += (n + 63) & ~(size_t)63; return p;
    };
    size_t degO[5], cdegO[5];
    for (int l = 0; l < 5; l++) degO[l]  = alw(NSa[l]);          // edge hist bins
    for (int l = 0; l < 5; l++) cdegO[l] = alw(NSa[l + 1]);      // cluster bins
    size_t sqO = alw(8);
    size_t zeroWords = off;                       // everything above zero-init
    size_t rpO[5], crpO[5], eidO[5], cnidO[5];
    for (int l = 0; l < 5; l++) rpO[l]   = alw(NSa[l] + 1);
    for (int l = 0; l < 5; l++) crpO[l]  = alw(NSa[l + 1] + 1);
    for (int l = 0; l < 5; l++) eidO[l]  = alw(ESa[l]);
    for (int l = 0; l < 5; l++) cnidO[l] = alw(NSa[l]);
    size_t yO = alw((size_t)65536 * 12);          // max N*CO (reused per level)
    size_t xnO[5], pnO[5];
    for (int l = 0; l < 5; l++) xnO[l] = alw((size_t)NSa[l + 1] * (COa[l] + 3));
    for (int l = 0; l < 5; l++) pnO[l] = alw((size_t)NSa[l + 1] * 3);

    hipMemsetAsync(d_ws, 0, zeroWords * 4, stream);

    // ---- CSR builds for all 5 levels (edge-by-dst + node-by-cluster) ----
    SegArgs sa{};
    int total = 0;
    for (int l = 0; l < 5; l++) {
        sa.idx[l] = (const int*)d_in[3 + 10 * l];      // dst
        sa.cnt[l] = wsw + degO[l];
        sa.rp [l] = wsw + rpO[l];
        sa.out[l] = wsw + eidO[l];
        sa.n  [l] = ESa[l];                            // elements = edges
        sa.nb [l] = NSa[l];                            // bins = nodes
        sa.idx[5 + l] = (const int*)d_in[5 + 10 * l];  // cluster
        sa.cnt[5 + l] = wsw + cdegO[l];
        sa.rp [5 + l] = wsw + crpO[l];
        sa.out[5 + l] = wsw + cnidO[l];
        sa.n  [5 + l] = NSa[l];                        // elements = nodes
        sa.nb [5 + l] = NSa[l + 1];                    // bins = clusters
        total += ESa[l] + NSa[l];
    }
    hist_all_k   <<<(total + 255) / 256, 256, 0, stream>>>(sa, total);
    scan_all_k   <<<10, 1024, 0, stream>>>(sa);
    scatter_all_k<<<(total + 255) / 256, 256, 0, stream>>>(sa, total);

    float* yb  = (float*)(wsw + yO);
    float* sqp = (float*)(wsw + sqO);

#define LVL(l, CI_, CO_, OW_) do {                                             \
    const float* xin   = ((l) == 0) ? x0   : (const float*)(wsw + xnO[(l)-1]); \
    const float* posin = ((l) == 0) ? pos0 : (const float*)(wsw + pnO[(l)-1]); \
    int N = NSa[(l)], NN = NSa[(l) + 1];                                       \
    constexpr int G_ = (CO_) / (OW_);                                          \
    node_conv_k<CI_, CO_, OW_><<<(N * G_ + 255) / 256, 256, 0, stream>>>(      \
        N, wsw + rpO[(l)], wsw + eidO[(l)],                                    \
        (const int*)d_in[2 + 10 * (l)], (const float*)d_in[4 + 10 * (l)],      \
        (const float*)d_in[6 + 10 * (l)], (const float*)d_in[7 + 10 * (l)],    \
        (const float*)d_in[8 + 10 * (l)], (const float*)d_in[9 + 10 * (l)],    \
        (const float*)d_in[10 + 10 * (l)], (const float*)d_in[11 + 10 * (l)],  \
        xin, yb, sqp + (l));                                                   \
    pool_k<CO_><<<(NN * ((CO_) + 3) + 255) / 256, 256, 0, stream>>>(           \
        NN, wsw + crpO[(l)], wsw + cnidO[(l)], yb, posin,                      \
        (float*)(wsw + xnO[(l)]), (float*)(wsw + pnO[(l)]));                   \
} while (0)

    LVL(0, 1, 12, 4);
    LVL(1, 15, 20, 4);
    LVL(2, 23, 28, 4);
    LVL(3, 31, 36, 4);
    LVL(4, 39, 44, 4);
#undef LVL

    fc_k<<<1, 128, 0, stream>>>((const float*)(wsw + xnO[4]),
                                (const float*)d_in[52], (const float*)d_in[53],
                                sqp, (float*)d_out);
}

// Round 5
// 641.794 us; speedup vs baseline: 2.6265x; 1.9435x over previous
//
#include <hip/hip_runtime.h>
#include <math.h>

// ---------------------------------------------------------------------------
// Net_37512244363273: 5-level edge-conditioned graph conv + voxel pooling + FC
// Round 5: deep levels (L2-L4) were parallelism-collapsed (L3: 36 blocks,
// 1.1% occupancy, 214 us). Fixes:
//  (a) factored conv: msg = b2.S0 + w2.SK with S0=sum_e x[src],
//      SK[k]=sum_e h_k x[src]  -> 10x less work, and
//  (b) block-per-node cooperative kernel for L1-L4 (phase A over 6*CI lanes,
//      phase B over CO lanes), ~10 KB LDS, 8 blocks/CU.
//  (c) Sum(We^2) factored into global per-level h-stats (H1[5],H2[15]) x
//      weight dot products -> two tiny kernels, off the hot path.
// L0 (CI=1) keeps the thread-per-(node,group) gather kernel. Zero float
// scatter atomics anywhere. Workspace ~9.8 MB.
// Output: [8,10] log_softmax (80) + closs = 81 floats.
// ---------------------------------------------------------------------------

// ---- segment descriptor for the 10 CSR builds (5 edge-dst + 5 cluster) ----
struct SegArgs {
    const int* idx[10];   // dst arrays (seg 0-4), cluster arrays (seg 5-9)
    int*       cnt[10];   // histogram (nb bins, zero-init; destroyed by scatter)
    int*       rp [10];   // exclusive scan out, nb+1 entries (rp[nb] = total)
    int*       out[10];   // CSR payload: eid / cnid (source index)
    int        n  [10];   // number of index elements (edges / nodes)
    int        nb [10];   // number of histogram bins  (nodes / clusters)
};

__global__ __launch_bounds__(256) void hist_all_k(SegArgs a, int total) {
    int t = blockIdx.x * 256 + threadIdx.x;
    if (t >= total) return;
    int start = 0;
    for (int s = 0; s < 10; s++) {
        if (t < start + a.n[s]) {
            atomicAdd(&a.cnt[s][a.idx[s][t - start]], 1);
            return;
        }
        start += a.n[s];
    }
}

// one block per segment; chunked exclusive scan over nb bins (nb <= 65536)
__global__ __launch_bounds__(1024) void scan_all_k(SegArgs a) {
    int b = blockIdx.x;
    const int* in = a.cnt[b];
    int* out = a.rp[b];
    int nb = a.nb[b];
    __shared__ int part[1024];
    int t = threadIdx.x;
    int chunk = (nb + 1023) >> 10;
    int lo = t * chunk; if (lo > nb) lo = nb;
    int hi = lo + chunk; if (hi > nb) hi = nb;
    int s = 0;
    for (int i = lo; i < hi; i++) s += in[i];
    part[t] = s;
    __syncthreads();
    for (int d = 1; d < 1024; d <<= 1) {
        int v = (t >= d) ? part[t - d] : 0;
        __syncthreads();
        part[t] += v;
        __syncthreads();
    }
    int run = part[t] - s;                 // exclusive prefix of this chunk
    for (int i = lo; i < hi; i++) { out[i] = run; run += in[i]; }
    if (t == 1023) out[nb] = run;          // total
}

// countdown-scatter: reuses cnt as cursor (slot order irrelevant for
// sum/mean/max). cnt is destroyed.
__global__ __launch_bounds__(256) void scatter_all_k(SegArgs a, int total) {
    int t = blockIdx.x * 256 + threadIdx.x;
    if (t >= total) return;
    int start = 0;
    for (int s = 0; s < 10; s++) {
        if (t < start + a.n[s]) {
            int i = t - start;
            int d = a.idx[s][i];
            int p = atomicSub(&a.cnt[s][d], 1) - 1;
            a.out[s][a.rp[s][d] + p] = i;
            return;
        }
        start += a.n[s];
    }
}

// ---------------------------------------------------------------------------
// hstats_k: per-level h statistics over ALL edges:
//   H[l] = { H1[k]=sum_e h_ek (5), H2[p]=sum_e h_ek*h_ek' for k<=k' (15) }.
// Blocks are statically partitioned across levels; K edges per thread.
// ---------------------------------------------------------------------------
struct HArgs {
    const float* eattr[5];
    const float* w1[5];
    const float* b1[5];
    float*       H;        // [5][20], zero-init
    int          E[5];
    int          bstart[6];
};

__global__ __launch_bounds__(256) void hstats_k(HArgs a) {
    const int K = 32;
    int b = blockIdx.x, l = 0;
    while (l < 4 && b >= a.bstart[l + 1]) l++;
    int bloc = b - a.bstart[l];
    const float* ea = a.eattr[l];
    float w1r[15], b1r[5];
    #pragma unroll
    for (int i = 0; i < 15; i++) w1r[i] = a.w1[l][i];
    #pragma unroll
    for (int i = 0; i < 5; i++)  b1r[i] = a.b1[l][i];

    float acc[20];
    #pragma unroll
    for (int i = 0; i < 20; i++) acc[i] = 0.f;

    int base = bloc * 256 * K + threadIdx.x;
    for (int it = 0; it < K; it++) {
        int e = base + it * 256;
        if (e < a.E[l]) {
            float e0 = ea[e * 3], e1 = ea[e * 3 + 1], e2 = ea[e * 3 + 2];
            float h[5];
            #pragma unroll
            for (int k = 0; k < 5; k++)
                h[k] = tanhf(e0 * w1r[k] + e1 * w1r[5 + k] + e2 * w1r[10 + k] + b1r[k]);
            int p = 5;
            #pragma unroll
            for (int k = 0; k < 5; k++) {
                acc[k] += h[k];
                #pragma unroll
                for (int k2 = k; k2 < 5; k2++) acc[p++] += h[k] * h[k2];
            }
        }
    }
    // block reduce 20 values
    __shared__ float red[4][20];
    int wid = threadIdx.x >> 6, lane = threadIdx.x & 63;
    #pragma unroll
    for (int v = 0; v < 20; v++) {
        float s = acc[v];
        #pragma unroll
        for (int off = 32; off; off >>= 1) s += __shfl_down(s, off);
        if (lane == 0) red[wid][v] = s;
    }
    __syncthreads();
    if (threadIdx.x < 20) {
        float s = red[0][threadIdx.x] + red[1][threadIdx.x] +
                  red[2][threadIdx.x] + red[3][threadIdx.x];
        atomicAdd(&a.H[l * 20 + threadIdx.x], s);
    }
}

// ---------------------------------------------------------------------------
// wstats_k: one wave per level. sq_l = E*sum(b2^2) + 2*sum_k B2W[k]*H1[k]
//   + sum_{k<=k'} (1 or 2)*W2dot[kk']*H2[kk'], with the 21 weight dot
// products computed here by striding io over CI*CO.
// ---------------------------------------------------------------------------
struct WArgs {
    const float* w2[5];
    const float* b2[5];
    const float* H;        // [5][20]
    float*       sq;       // [5] out (raw totals)
    int          cico[5];
    int          E[5];
};

__global__ __launch_bounds__(64) void wstats_k(WArgs a) {
    int l = blockIdx.x;
    const float* w2 = a.w2[l];
    const float* b2 = a.b2[l];
    int cico = a.cico[l];
    float d[21];                      // [0..14]=w2k.w2k' (k<=k'), [15..19]=b2.w2k, [20]=b2.b2
    #pragma unroll
    for (int i = 0; i < 21; i++) d[i] = 0.f;
    for (int u = threadIdx.x; u < cico; u += 64) {
        float b = b2[u];
        float w[5];
        #pragma unroll
        for (int k = 0; k < 5; k++) w[k] = w2[k * cico + u];
        int p = 0;
        #pragma unroll
        for (int k = 0; k < 5; k++) {
            #pragma unroll
            for (int k2 = k; k2 < 5; k2++) d[p++] += w[k] * w[k2];
        }
        #pragma unroll
        for (int k = 0; k < 5; k++) d[15 + k] += b * w[k];
        d[20] += b * b;
    }
    #pragma unroll
    for (int i = 0; i < 21; i++) {
        #pragma unroll
        for (int off = 32; off; off >>= 1) d[i] += __shfl_down(d[i], off);
    }
    if (threadIdx.x == 0) {
        const float* H1 = a.H + l * 20;
        const float* H2 = H1 + 5;
        float sq = (float)a.E[l] * d[20];
        #pragma unroll
        for (int k = 0; k < 5; k++) sq += 2.f * d[15 + k] * H1[k];
        int p = 0;
        #pragma unroll
        for (int k = 0; k < 5; k++) {
            #pragma unroll
            for (int k2 = k; k2 < 5; k2++) {
                sq += ((k == k2) ? 1.f : 2.f) * d[p] * H2[p];
                p++;
            }
        }
        a.sq[l] = sq;
    }
}

// ---------------------------------------------------------------------------
// node_conv_k (L0 only, CI=1): thread per (node, group of OW channels),
// walks CSR edge list, computes h and We columns on the fly. No sq here.
// ---------------------------------------------------------------------------
template<int CI, int CO, int OW>
__global__ __launch_bounds__(256) void node_conv_k(
    int N,
    const int* __restrict__ rp, const int* __restrict__ eid,
    const int* __restrict__ src, const float* __restrict__ eattr,
    const float* __restrict__ w1, const float* __restrict__ b1,
    const float* __restrict__ w2, const float* __restrict__ b2,
    const float* __restrict__ root, const float* __restrict__ bias,
    const float* __restrict__ x, float* __restrict__ y)
{
    constexpr int G    = CO / OW;
    constexpr int CICO = CI * CO;
    __shared__ float w1s[15], b1s[5];
    __shared__ float w2s[5 * CICO], b2s[CICO], roots[CICO], biass[CO];
    for (int t = threadIdx.x; t < 5 * CICO; t += 256) w2s[t]   = w2[t];
    for (int t = threadIdx.x; t < CICO;     t += 256) b2s[t]   = b2[t];
    for (int t = threadIdx.x; t < CICO;     t += 256) roots[t] = root[t];
    for (int t = threadIdx.x; t < CO;       t += 256) biass[t] = bias[t];
    if (threadIdx.x < 15) w1s[threadIdx.x] = w1[threadIdx.x];
    if (threadIdx.x < 5)  b1s[threadIdx.x] = b1[threadIdx.x];
    __syncthreads();

    int t = blockIdx.x * 256 + threadIdx.x;
    if (t >= N * G) return;
    int v  = t / G;
    int ob = (t % G) * OW;
    int r0 = rp[v], r1 = rp[v + 1];
    int d  = r1 - r0;
    float acc[OW];
    #pragma unroll
    for (int oo = 0; oo < OW; oo++) acc[oo] = 0.f;

    for (int j = r0; j < r1; j++) {
        int e = eid[j];
        float ea0 = eattr[e * 3], ea1 = eattr[e * 3 + 1], ea2 = eattr[e * 3 + 2];
        float h[5];
        #pragma unroll
        for (int k = 0; k < 5; k++)
            h[k] = tanhf(ea0 * w1s[k] + ea1 * w1s[5 + k] + ea2 * w1s[10 + k] + b1s[k]);
        int sv = src[e];
        for (int i = 0; i < CI; i++) {
            float xi = x[sv * CI + i];
            #pragma unroll
            for (int oo = 0; oo < OW; oo++) {
                int o = ob + oo;
                float we = b2s[i * CO + o];
                #pragma unroll
                for (int k = 0; k < 5; k++) we += h[k] * w2s[k * CICO + i * CO + o];
                acc[oo] += xi * we;
            }
        }
    }
    float inv = 1.f / fmaxf((float)d, 1.f);
    #pragma unroll
    for (int oo = 0; oo < OW; oo++) acc[oo] *= inv;
    for (int i = 0; i < CI; i++) {
        float xi = x[v * CI + i];
        #pragma unroll
        for (int oo = 0; oo < OW; oo++)
            acc[oo] += xi * roots[i * CO + ob + oo];
    }
    #pragma unroll
    for (int oo = 0; oo < OW; oo++)
        y[(size_t)v * CO + ob + oo] = acc[oo] + biass[ob + oo];
}

// ---------------------------------------------------------------------------
// coop_conv_k (L1-L4): one block (256 threads) per node v.
// Phase A (per edge-chunk of CH): stage eid/src, h (with h[0]=1 slot) and
// x[src] rows in LDS; 6*CI lanes accumulate S[(i,k6)] += h6[j][k6]*xs[j][i].
// Phase B: CO lanes contract S with b2/w2 (global, L2-cached, coalesced),
// add mean-div, x[v]@root, bias -> y. No atomics, no sq.
// ---------------------------------------------------------------------------
template<int CI, int CO>
__global__ __launch_bounds__(256) void coop_conv_k(
    const int* __restrict__ rp, const int* __restrict__ eid,
    const int* __restrict__ src, const float* __restrict__ eattr,
    const float* __restrict__ w1, const float* __restrict__ b1,
    const float* __restrict__ w2, const float* __restrict__ b2,
    const float* __restrict__ root, const float* __restrict__ bias,
    const float* __restrict__ x, float* __restrict__ y)
{
    constexpr int CH   = 48;               // edges per chunk (CH*5 <= 240)
    constexpr int CICO = CI * CO;
    static_assert(6 * CI <= 256, "phase-A lanes");
    __shared__ float w1s[20];
    __shared__ int   eb[CH], svb[CH];
    __shared__ float hb[CH * 6];           // [j][k6], k6=0 -> 1.0
    __shared__ float xs[CH * CI];          // [j][i]
    __shared__ float S[6 * CI];            // [i*6 + k6]

    int t = threadIdx.x;
    int v = blockIdx.x;
    if (t < 20) w1s[t] = (t < 15) ? w1[t] : b1[t - 15];
    int r0 = rp[v], r1 = rp[v + 1];
    int d  = r1 - r0;
    float acc = 0.f;                       // this thread's (i,k6) accumulator

    for (int c0 = r0; c0 < r1; c0 += CH) {
        int cn = min(CH, r1 - c0);
        if (t < cn) {
            int e = eid[c0 + t];
            eb[t]  = e;
            svb[t] = src[e];
            hb[t * 6] = 1.f;
        }
        __syncthreads();                   // eb/svb ready (also w1s, 1st iter)
        if (t < cn * 5) {
            int j = t / 5, k = t % 5;
            int e = eb[j];
            float e0 = eattr[e * 3], e1 = eattr[e * 3 + 1], e2 = eattr[e * 3 + 2];
            hb[j * 6 + 1 + k] =
                tanhf(e0 * w1s[k] + e1 * w1s[5 + k] + e2 * w1s[10 + k] + w1s[15 + k]);
        }
        for (int u = t; u < cn * CI; u += 256)
            xs[u] = x[(size_t)svb[u / CI] * CI + (u % CI)];
        __syncthreads();                   // hb/xs ready
        if (t < 6 * CI) {
            int i = t / 6, k6 = t % 6;
            for (int j = 0; j < cn; j++)
                acc += hb[j * 6 + k6] * xs[j * CI + i];
        }
        __syncthreads();                   // protect hb/xs before next chunk
    }

    if (t < 6 * CI) S[t] = acc;
    __syncthreads();

    if (t < CO) {
        float m = 0.f;
        for (int i = 0; i < CI; i++) {
            m += b2[i * CO + t] * S[i * 6];
            #pragma unroll
            for (int k = 0; k < 5; k++)
                m += w2[k * CICO + i * CO + t] * S[i * 6 + 1 + k];
        }
        m /= fmaxf((float)d, 1.f);
        for (int i = 0; i < CI; i++)
            m += x[(size_t)v * CI + i] * root[i * CO + t];
        y[(size_t)v * CO + t] = m + bias[t];
    }
}

// ---------------------------------------------------------------------------
// pool_k: one thread per (cluster, channel). Gather-max features, gather-mean
// pos via cluster CSR. Empty cluster -> 0 (matches isfinite guard in ref).
// ---------------------------------------------------------------------------
template<int CO>
__global__ __launch_bounds__(256) void pool_k(
    int NN,
    const int* __restrict__ crp, const int* __restrict__ cnid,
    const float* __restrict__ y, const float* __restrict__ pos,
    float* __restrict__ xn,                // [NN, CO+3]
    float* __restrict__ pn)                // [NN, 3]
{
    int t = blockIdx.x * 256 + threadIdx.x;
    if (t >= NN * (CO + 3)) return;
    int c = t / (CO + 3), o = t % (CO + 3);
    int r0 = crp[c], r1 = crp[c + 1];
    int d = r1 - r0;
    if (o < CO) {
        float m = -INFINITY;
        for (int j = r0; j < r1; j++)
            m = fmaxf(m, y[(size_t)cnid[j] * CO + o]);
        if (d == 0 || !isfinite(m)) m = 0.f;
        xn[c * (CO + 3) + o] = m;
    } else {
        int k = o - CO;
        float sum = 0.f;
        for (int j = r0; j < r1; j++)
            sum += pos[cnid[j] * 3 + k];
        float pm = sum / fmaxf((float)d, 1.f);
        xn[c * (CO + 3) + CO + k] = pm;
        pn[c * 3 + k] = pm;
    }
}

// ---------------------------------------------------------------------------
// fc_k: single block. logits = feat@fc_w + fc_b; log_softmax; closs.
// ---------------------------------------------------------------------------
__global__ __launch_bounds__(128) void fc_k(
    const float* __restrict__ x5,          // [64,47] == [8,376]
    const float* __restrict__ fc_w, const float* __restrict__ fc_b,
    const float* __restrict__ sq, float* __restrict__ out)
{
    __shared__ float feat[8 * 376];
    __shared__ float logit[80];
    __shared__ float roff[8];
    for (int t = threadIdx.x; t < 8 * 376; t += 128) feat[t] = x5[t];
    __syncthreads();
    int t = threadIdx.x;
    if (t < 80) {
        int b = t / 10, j = t % 10;
        float acc = fc_b[j];
        for (int k = 0; k < 376; k++) acc += feat[b * 376 + k] * fc_w[k * 10 + j];
        logit[t] = acc;
    }
    __syncthreads();
    if (t < 8) {
        float m = -1e30f;
        for (int j = 0; j < 10; j++) m = fmaxf(m, logit[t * 10 + j]);
        float ssum = 0.f;
        for (int j = 0; j < 10; j++) ssum += expf(logit[t * 10 + j] - m);
        roff[t] = m + logf(ssum);
    }
    __syncthreads();
    if (t < 80) out[t] = logit[t] - roff[t / 10];
    if (t == 0) {
        float closs = 0.f;
        closs += sq[0] * (1.0f / 12582912.0f);   // 1048576 * 1  * 12
        closs += sq[1] * (1.0f / 78643200.0f);   // 262144  * 15 * 20
        closs += sq[2] * (1.0f / 42205184.0f);   // 65536   * 23 * 28
        closs += sq[3] * (1.0f / 18284544.0f);   // 16384   * 31 * 36
        closs += sq[4] * (1.0f / 7028736.0f);    // 4096    * 39 * 44
        out[80] = closs;
    }
}

// ---------------------------------------------------------------------------

extern "C" void kernel_launch(void* const* d_in, const int* in_sizes, int n_in,
                              void* d_out, int out_size, void* d_ws, size_t ws_size,
                              hipStream_t stream)
{
    static const int NSa[6] = {65536, 16384, 4096, 1024, 256, 64};
    static const int ESa[5] = {1048576, 262144, 65536, 16384, 4096};
    static const int COa[5] = {12, 20, 28, 36, 44};
    static const int CIa[5] = {1, 15, 23, 31, 39};

    const float* x0   = (const float*)d_in[0];
    const float* pos0 = (const float*)d_in[1];

    // ---- workspace layout, 4-byte words, 256B-aligned chunks (~9.8 MB) ----
    int* wsw = (int*)d_ws;
    size_t off = 0;
    auto alw = [&](size_t n) -> size_t {
        size_t p = off; off += (n + 63) & ~(size_t)63; return p;
    };
    size_t degO[5], cdegO[5];
    for (int l = 0; l < 5; l++) degO[l]  = alw(NSa[l]);          // edge hist bins
    for (int l = 0; l < 5; l++) cdegO[l] = alw(NSa[l + 1]);      // cluster bins
    size_t HO = alw(100);                          // H[5][20] (atomic target)
    size_t zeroWords = off;                        // zero-init through here
    size_t rpO[5], crpO[5], eidO[5], cnidO[5];
    for (int l = 0; l < 5; l++) rpO[l]   = alw(NSa[l] + 1);
    for (int l = 0; l < 5; l++) crpO[l]  = alw(NSa[l + 1] + 1);
    for (int l = 0; l < 5; l++) eidO[l]  = alw(ESa[l]);
    for (int l = 0; l < 5; l++) cnidO[l] = alw(NSa[l]);
    size_t yO  = alw((size_t)65536 * 12);          // max N*CO (reused per level)
    size_t sqO = alw(8);                           // wstats output
    size_t xnO[5], pnO[5];
    for (int l = 0; l < 5; l++) xnO[l] = alw((size_t)NSa[l + 1] * (COa[l] + 3));
    for (int l = 0; l < 5; l++) pnO[l] = alw((size_t)NSa[l + 1] * 3);

    hipMemsetAsync(d_ws, 0, zeroWords * 4, stream);

    // ---- CSR builds for all 5 levels (edge-by-dst + node-by-cluster) ----
    SegArgs sa{};
    int total = 0;
    for (int l = 0; l < 5; l++) {
        sa.idx[l] = (const int*)d_in[3 + 10 * l];      // dst
        sa.cnt[l] = wsw + degO[l];
        sa.rp [l] = wsw + rpO[l];
        sa.out[l] = wsw + eidO[l];
        sa.n  [l] = ESa[l];
        sa.nb [l] = NSa[l];
        sa.idx[5 + l] = (const int*)d_in[5 + 10 * l];  // cluster
        sa.cnt[5 + l] = wsw + cdegO[l];
        sa.rp [5 + l] = wsw + crpO[l];
        sa.out[5 + l] = wsw + cnidO[l];
        sa.n  [5 + l] = NSa[l];
        sa.nb [5 + l] = NSa[l + 1];
        total += ESa[l] + NSa[l];
    }
    hist_all_k   <<<(total + 255) / 256, 256, 0, stream>>>(sa, total);
    scan_all_k   <<<10, 1024, 0, stream>>>(sa);
    scatter_all_k<<<(total + 255) / 256, 256, 0, stream>>>(sa, total);

    // ---- h statistics + weight stats -> sq totals ----
    HArgs ha{};
    int bs = 0;
    for (int l = 0; l < 5; l++) {
        ha.eattr[l] = (const float*)d_in[4 + 10 * l];
        ha.w1[l]    = (const float*)d_in[6 + 10 * l];
        ha.b1[l]    = (const float*)d_in[7 + 10 * l];
        ha.E[l]     = ESa[l];
        ha.bstart[l] = bs;
        bs += (ESa[l] + 256 * 32 - 1) / (256 * 32);
    }
    ha.bstart[5] = bs;
    ha.H = (float*)(wsw + HO);
    hstats_k<<<bs, 256, 0, stream>>>(ha);

    WArgs wa{};
    for (int l = 0; l < 5; l++) {
        wa.w2[l]   = (const float*)d_in[8 + 10 * l];
        wa.b2[l]   = (const float*)d_in[9 + 10 * l];
        wa.cico[l] = CIa[l] * COa[l];
        wa.E[l]    = ESa[l];
    }
    wa.H  = (const float*)(wsw + HO);
    wa.sq = (float*)(wsw + sqO);
    wstats_k<<<5, 64, 0, stream>>>(wa);

    float* yb = (float*)(wsw + yO);

    // ---- level 0: thread-per-(node,group) (CI=1) ----
    node_conv_k<1, 12, 6><<<(NSa[0] * 2 + 255) / 256, 256, 0, stream>>>(
        NSa[0], wsw + rpO[0], wsw + eidO[0],
        (const int*)d_in[2], (const float*)d_in[4],
        (const float*)d_in[6], (const float*)d_in[7],
        (const float*)d_in[8], (const float*)d_in[9],
        (const float*)d_in[10], (const float*)d_in[11], x0, yb);
    pool_k<12><<<(NSa[1] * 15 + 255) / 256, 256, 0, stream>>>(
        NSa[1], wsw + crpO[0], wsw + cnidO[0], yb, pos0,
        (float*)(wsw + xnO[0]), (float*)(wsw + pnO[0]));

    // ---- levels 1-4: block-per-node cooperative ----
#define LVLC(l, CI_, CO_) do {                                                 \
    const float* xin   = (const float*)(wsw + xnO[(l) - 1]);                   \
    const float* posin = (const float*)(wsw + pnO[(l) - 1]);                   \
    int N = NSa[(l)], NN = NSa[(l) + 1];                                       \
    coop_conv_k<CI_, CO_><<<N, 256, 0, stream>>>(                              \
        wsw + rpO[(l)], wsw + eidO[(l)],                                       \
        (const int*)d_in[2 + 10 * (l)], (const float*)d_in[4 + 10 * (l)],      \
        (const float*)d_in[6 + 10 * (l)], (const float*)d_in[7 + 10 * (l)],    \
        (const float*)d_in[8 + 10 * (l)], (const float*)d_in[9 + 10 * (l)],    \
        (const float*)d_in[10 + 10 * (l)], (const float*)d_in[11 + 10 * (l)],  \
        xin, yb);                                                              \
    pool_k<CO_><<<(NN * ((CO_) + 3) + 255) / 256, 256, 0, stream>>>(           \
        NN, wsw + crpO[(l)], wsw + cnidO[(l)], yb, posin,                      \
        (float*)(wsw + xnO[(l)]), (float*)(wsw + pnO[(l)]));                   \
} while (0)

    LVLC(1, 15, 20);
    LVLC(2, 23, 28);
    LVLC(3, 31, 36);
    LVLC(4, 39, 44);
#undef LVLC

    fc_k<<<1, 128, 0, stream>>>((const float*)(wsw + xnO[4]),
                                (const float*)d_in[52], (const float*)d_in[53],
                                (const float*)(wsw + sqO), (float*)d_out);
}

// Round 6
// 612.127 us; speedup vs baseline: 2.7538x; 1.0485x over previous
//
#include <hip/hip_runtime.h>
#include <math.h>

// ---------------------------------------------------------------------------
// Net_37512244363273: 5-level edge-conditioned graph conv + voxel pooling + FC
// Round 6: round 5's top dispatch was scatter_all_k (110 us, WRITE_SIZE 96 MB
// for 5.7 MB payload -- random 4B stores dirty whole 64B lines across
// multiple non-coherent XCD L2s). Fix: XCD-bucketed scatter. All nb are
// powers of 2; bucket = d >> (log2(nb)-3), block processes only its bucket
// (bucket = blockIdx % 8 -> one XCD under round-robin dispatch). Writes for a
// bucket land in one contiguous ~1/8 slice -> single-L2 dirty lines, merged,
// written back once. 8x idx read amplification (~46 MB, L2/L3-served).
// Everything else unchanged from round 5 for clean attribution.
// Output: [8,10] log_softmax (80) + closs = 81 floats.
// ---------------------------------------------------------------------------

#define NBUCK 8

// ---- segment descriptor for the 10 CSR builds (5 edge-dst + 5 cluster) ----
struct SegArgs {
    const int* idx[10];   // dst arrays (seg 0-4), cluster arrays (seg 5-9)
    int*       cnt[10];   // histogram (nb bins, zero-init; destroyed by scatter)
    int*       rp [10];   // exclusive scan out, nb+1 entries (rp[nb] = total)
    int*       out[10];   // CSR payload: eid / cnid (source index)
    int        n  [10];   // number of index elements (edges / nodes)
    int        nb [10];   // number of histogram bins  (nodes / clusters)
    int        shift[10]; // log2(nb) - 3 (bucket = d >> shift)
    int        tstart[11];// cumulative 256-thread tiles per segment
};

__global__ __launch_bounds__(256) void hist_all_k(SegArgs a, int total) {
    int t = blockIdx.x * 256 + threadIdx.x;
    if (t >= total) return;
    int start = 0;
    for (int s = 0; s < 10; s++) {
        if (t < start + a.n[s]) {
            atomicAdd(&a.cnt[s][a.idx[s][t - start]], 1);
            return;
        }
        start += a.n[s];
    }
}

// one block per segment; chunked exclusive scan over nb bins (nb <= 65536)
__global__ __launch_bounds__(1024) void scan_all_k(SegArgs a) {
    int b = blockIdx.x;
    const int* in = a.cnt[b];
    int* out = a.rp[b];
    int nb = a.nb[b];
    __shared__ int part[1024];
    int t = threadIdx.x;
    int chunk = (nb + 1023) >> 10;
    int lo = t * chunk; if (lo > nb) lo = nb;
    int hi = lo + chunk; if (hi > nb) hi = nb;
    int s = 0;
    for (int i = lo; i < hi; i++) s += in[i];
    part[t] = s;
    __syncthreads();
    for (int d = 1; d < 1024; d <<= 1) {
        int v = (t >= d) ? part[t - d] : 0;
        __syncthreads();
        part[t] += v;
        __syncthreads();
    }
    int run = part[t] - s;                 // exclusive prefix of this chunk
    for (int i = lo; i < hi; i++) { out[i] = run; run += in[i]; }
    if (t == 1023) out[nb] = run;          // total
}

// XCD-bucketed countdown-scatter. flat block B: bucket = B % NBUCK (-> XCD
// B%8 under round-robin dispatch), tile = B / NBUCK. Each tile is scanned by
// all 8 buckets; a thread commits only if its dst falls in the block's
// bucket range. cnt is reused as a countdown cursor (destroyed).
__global__ __launch_bounds__(256) void scatter_all_k(SegArgs a) {
    int B = blockIdx.x;
    int bucket = B % NBUCK;
    int T = B / NBUCK;
    // find segment of tile T
    int s = 0;
    while (s < 9 && T >= a.tstart[s + 1]) s++;
    int i = (T - a.tstart[s]) * 256 + threadIdx.x;
    if (i >= a.n[s]) return;
    int d = a.idx[s][i];
    if ((d >> a.shift[s]) != bucket) return;
    int p = atomicSub(&a.cnt[s][d], 1) - 1;
    a.out[s][a.rp[s][d] + p] = i;
}

// ---------------------------------------------------------------------------
// hstats_k: per-level h statistics over ALL edges:
//   H[l] = { H1[k]=sum_e h_ek (5), H2[p]=sum_e h_ek*h_ek' for k<=k' (15) }.
// ---------------------------------------------------------------------------
struct HArgs {
    const float* eattr[5];
    const float* w1[5];
    const float* b1[5];
    float*       H;        // [5][20], zero-init
    int          E[5];
    int          bstart[6];
};

__global__ __launch_bounds__(256) void hstats_k(HArgs a) {
    const int K = 32;
    int b = blockIdx.x, l = 0;
    while (l < 4 && b >= a.bstart[l + 1]) l++;
    int bloc = b - a.bstart[l];
    const float* ea = a.eattr[l];
    float w1r[15], b1r[5];
    #pragma unroll
    for (int i = 0; i < 15; i++) w1r[i] = a.w1[l][i];
    #pragma unroll
    for (int i = 0; i < 5; i++)  b1r[i] = a.b1[l][i];

    float acc[20];
    #pragma unroll
    for (int i = 0; i < 20; i++) acc[i] = 0.f;

    int base = bloc * 256 * K + threadIdx.x;
    for (int it = 0; it < K; it++) {
        int e = base + it * 256;
        if (e < a.E[l]) {
            float e0 = ea[e * 3], e1 = ea[e * 3 + 1], e2 = ea[e * 3 + 2];
            float h[5];
            #pragma unroll
            for (int k = 0; k < 5; k++)
                h[k] = tanhf(e0 * w1r[k] + e1 * w1r[5 + k] + e2 * w1r[10 + k] + b1r[k]);
            int p = 5;
            #pragma unroll
            for (int k = 0; k < 5; k++) {
                acc[k] += h[k];
                #pragma unroll
                for (int k2 = k; k2 < 5; k2++) acc[p++] += h[k] * h[k2];
            }
        }
    }
    __shared__ float red[4][20];
    int wid = threadIdx.x >> 6, lane = threadIdx.x & 63;
    #pragma unroll
    for (int v = 0; v < 20; v++) {
        float s = acc[v];
        #pragma unroll
        for (int off = 32; off; off >>= 1) s += __shfl_down(s, off);
        if (lane == 0) red[wid][v] = s;
    }
    __syncthreads();
    if (threadIdx.x < 20) {
        float s = red[0][threadIdx.x] + red[1][threadIdx.x] +
                  red[2][threadIdx.x] + red[3][threadIdx.x];
        atomicAdd(&a.H[l * 20 + threadIdx.x], s);
    }
}

// ---------------------------------------------------------------------------
// wstats_k: one wave per level. Contracts 21 weight dot-products with H.
// ---------------------------------------------------------------------------
struct WArgs {
    const float* w2[5];
    const float* b2[5];
    const float* H;        // [5][20]
    float*       sq;       // [5] out (raw totals)
    int          cico[5];
    int          E[5];
};

__global__ __launch_bounds__(64) void wstats_k(WArgs a) {
    int l = blockIdx.x;
    const float* w2 = a.w2[l];
    const float* b2 = a.b2[l];
    int cico = a.cico[l];
    float d[21];
    #pragma unroll
    for (int i = 0; i < 21; i++) d[i] = 0.f;
    for (int u = threadIdx.x; u < cico; u += 64) {
        float b = b2[u];
        float w[5];
        #pragma unroll
        for (int k = 0; k < 5; k++) w[k] = w2[k * cico + u];
        int p = 0;
        #pragma unroll
        for (int k = 0; k < 5; k++) {
            #pragma unroll
            for (int k2 = k; k2 < 5; k2++) d[p++] += w[k] * w[k2];
        }
        #pragma unroll
        for (int k = 0; k < 5; k++) d[15 + k] += b * w[k];
        d[20] += b * b;
    }
    #pragma unroll
    for (int i = 0; i < 21; i++) {
        #pragma unroll
        for (int off = 32; off; off >>= 1) d[i] += __shfl_down(d[i], off);
    }
    if (threadIdx.x == 0) {
        const float* H1 = a.H + l * 20;
        const float* H2 = H1 + 5;
        float sq = (float)a.E[l] * d[20];
        #pragma unroll
        for (int k = 0; k < 5; k++) sq += 2.f * d[15 + k] * H1[k];
        int p = 0;
        #pragma unroll
        for (int k = 0; k < 5; k++) {
            #pragma unroll
            for (int k2 = k; k2 < 5; k2++) {
                sq += ((k == k2) ? 1.f : 2.f) * d[p] * H2[p];
                p++;
            }
        }
        a.sq[l] = sq;
    }
}

// ---------------------------------------------------------------------------
// node_conv_k (L0 only, CI=1): thread per (node, group of OW channels).
// ---------------------------------------------------------------------------
template<int CI, int CO, int OW>
__global__ __launch_bounds__(256) void node_conv_k(
    int N,
    const int* __restrict__ rp, const int* __restrict__ eid,
    const int* __restrict__ src, const float* __restrict__ eattr,
    const float* __restrict__ w1, const float* __restrict__ b1,
    const float* __restrict__ w2, const float* __restrict__ b2,
    const float* __restrict__ root, const float* __restrict__ bias,
    const float* __restrict__ x, float* __restrict__ y)
{
    constexpr int G    = CO / OW;
    constexpr int CICO = CI * CO;
    __shared__ float w1s[15], b1s[5];
    __shared__ float w2s[5 * CICO], b2s[CICO], roots[CICO], biass[CO];
    for (int t = threadIdx.x; t < 5 * CICO; t += 256) w2s[t]   = w2[t];
    for (int t = threadIdx.x; t < CICO;     t += 256) b2s[t]   = b2[t];
    for (int t = threadIdx.x; t < CICO;     t += 256) roots[t] = root[t];
    for (int t = threadIdx.x; t < CO;       t += 256) biass[t] = bias[t];
    if (threadIdx.x < 15) w1s[threadIdx.x] = w1[threadIdx.x];
    if (threadIdx.x < 5)  b1s[threadIdx.x] = b1[threadIdx.x];
    __syncthreads();

    int t = blockIdx.x * 256 + threadIdx.x;
    if (t >= N * G) return;
    int v  = t / G;
    int ob = (t % G) * OW;
    int r0 = rp[v], r1 = rp[v + 1];
    int d  = r1 - r0;
    float acc[OW];
    #pragma unroll
    for (int oo = 0; oo < OW; oo++) acc[oo] = 0.f;

    for (int j = r0; j < r1; j++) {
        int e = eid[j];
        float ea0 = eattr[e * 3], ea1 = eattr[e * 3 + 1], ea2 = eattr[e * 3 + 2];
        float h[5];
        #pragma unroll
        for (int k = 0; k < 5; k++)
            h[k] = tanhf(ea0 * w1s[k] + ea1 * w1s[5 + k] + ea2 * w1s[10 + k] + b1s[k]);
        int sv = src[e];
        for (int i = 0; i < CI; i++) {
            float xi = x[sv * CI + i];
            #pragma unroll
            for (int oo = 0; oo < OW; oo++) {
                int o = ob + oo;
                float we = b2s[i * CO + o];
                #pragma unroll
                for (int k = 0; k < 5; k++) we += h[k] * w2s[k * CICO + i * CO + o];
                acc[oo] += xi * we;
            }
        }
    }
    float inv = 1.f / fmaxf((float)d, 1.f);
    #pragma unroll
    for (int oo = 0; oo < OW; oo++) acc[oo] *= inv;
    for (int i = 0; i < CI; i++) {
        float xi = x[v * CI + i];
        #pragma unroll
        for (int oo = 0; oo < OW; oo++)
            acc[oo] += xi * roots[i * CO + ob + oo];
    }
    #pragma unroll
    for (int oo = 0; oo < OW; oo++)
        y[(size_t)v * CO + ob + oo] = acc[oo] + biass[ob + oo];
}

// ---------------------------------------------------------------------------
// coop_conv_k (L1-L4): one block (256 threads) per node v. Factored conv:
// phase A accumulates S[(i,k6)] over edges via LDS-staged h and x rows;
// phase B contracts with b2/w2.
// ---------------------------------------------------------------------------
template<int CI, int CO>
__global__ __launch_bounds__(256) void coop_conv_k(
    const int* __restrict__ rp, const int* __restrict__ eid,
    const int* __restrict__ src, const float* __restrict__ eattr,
    const float* __restrict__ w1, const float* __restrict__ b1,
    const float* __restrict__ w2, const float* __restrict__ b2,
    const float* __restrict__ root, const float* __restrict__ bias,
    const float* __restrict__ x, float* __restrict__ y)
{
    constexpr int CH   = 48;               // edges per chunk (CH*5 <= 240)
    constexpr int CICO = CI * CO;
    static_assert(6 * CI <= 256, "phase-A lanes");
    __shared__ float w1s[20];
    __shared__ int   eb[CH], svb[CH];
    __shared__ float hb[CH * 6];           // [j][k6], k6=0 -> 1.0
    __shared__ float xs[CH * CI];          // [j][i]
    __shared__ float S[6 * CI];            // [i*6 + k6]

    int t = threadIdx.x;
    int v = blockIdx.x;
    if (t < 20) w1s[t] = (t < 15) ? w1[t] : b1[t - 15];
    int r0 = rp[v], r1 = rp[v + 1];
    int d  = r1 - r0;
    float acc = 0.f;                       // this thread's (i,k6) accumulator

    for (int c0 = r0; c0 < r1; c0 += CH) {
        int cn = min(CH, r1 - c0);
        if (t < cn) {
            int e = eid[c0 + t];
            eb[t]  = e;
            svb[t] = src[e];
            hb[t * 6] = 1.f;
        }
        __syncthreads();                   // eb/svb ready (also w1s, 1st iter)
        if (t < cn * 5) {
            int j = t / 5, k = t % 5;
            int e = eb[j];
            float e0 = eattr[e * 3], e1 = eattr[e * 3 + 1], e2 = eattr[e * 3 + 2];
            hb[j * 6 + 1 + k] =
                tanhf(e0 * w1s[k] + e1 * w1s[5 + k] + e2 * w1s[10 + k] + w1s[15 + k]);
        }
        for (int u = t; u < cn * CI; u += 256)
            xs[u] = x[(size_t)svb[u / CI] * CI + (u % CI)];
        __syncthreads();                   // hb/xs ready
        if (t < 6 * CI) {
            int i = t / 6, k6 = t % 6;
            for (int j = 0; j < cn; j++)
                acc += hb[j * 6 + k6] * xs[j * CI + i];
        }
        __syncthreads();                   // protect hb/xs before next chunk
    }

    if (t < 6 * CI) S[t] = acc;
    __syncthreads();

    if (t < CO) {
        float m = 0.f;
        for (int i = 0; i < CI; i++) {
            m += b2[i * CO + t] * S[i * 6];
            #pragma unroll
            for (int k = 0; k < 5; k++)
                m += w2[k * CICO + i * CO + t] * S[i * 6 + 1 + k];
        }
        m /= fmaxf((float)d, 1.f);
        for (int i = 0; i < CI; i++)
            m += x[(size_t)v * CI + i] * root[i * CO + t];
        y[(size_t)v * CO + t] = m + bias[t];
    }
}

// ---------------------------------------------------------------------------
// pool_k: one thread per (cluster, channel). Gather-max / gather-mean.
// ---------------------------------------------------------------------------
template<int CO>
__global__ __launch_bounds__(256) void pool_k(
    int NN,
    const int* __restrict__ crp, const int* __restrict__ cnid,
    const float* __restrict__ y, const float* __restrict__ pos,
    float* __restrict__ xn,                // [NN, CO+3]
    float* __restrict__ pn)                // [NN, 3]
{
    int t = blockIdx.x * 256 + threadIdx.x;
    if (t >= NN * (CO + 3)) return;
    int c = t / (CO + 3), o = t % (CO + 3);
    int r0 = crp[c], r1 = crp[c + 1];
    int d = r1 - r0;
    if (o < CO) {
        float m = -INFINITY;
        for (int j = r0; j < r1; j++)
            m = fmaxf(m, y[(size_t)cnid[j] * CO + o]);
        if (d == 0 || !isfinite(m)) m = 0.f;
        xn[c * (CO + 3) + o] = m;
    } else {
        int k = o - CO;
        float sum = 0.f;
        for (int j = r0; j < r1; j++)
            sum += pos[cnid[j] * 3 + k];
        float pm = sum / fmaxf((float)d, 1.f);
        xn[c * (CO + 3) + CO + k] = pm;
        pn[c * 3 + k] = pm;
    }
}

// ---------------------------------------------------------------------------
// fc_k: single block. logits = feat@fc_w + fc_b; log_softmax; closs.
// ---------------------------------------------------------------------------
__global__ __launch_bounds__(128) void fc_k(
    const float* __restrict__ x5,          // [64,47] == [8,376]
    const float* __restrict__ fc_w, const float* __restrict__ fc_b,
    const float* __restrict__ sq, float* __restrict__ out)
{
    __shared__ float feat[8 * 376];
    __shared__ float logit[80];
    __shared__ float roff[8];
    for (int t = threadIdx.x; t < 8 * 376; t += 128) feat[t] = x5[t];
    __syncthreads();
    int t = threadIdx.x;
    if (t < 80) {
        int b = t / 10, j = t % 10;
        float acc = fc_b[j];
        for (int k = 0; k < 376; k++) acc += feat[b * 376 + k] * fc_w[k * 10 + j];
        logit[t] = acc;
    }
    __syncthreads();
    if (t < 8) {
        float m = -1e30f;
        for (int j = 0; j < 10; j++) m = fmaxf(m, logit[t * 10 + j]);
        float ssum = 0.f;
        for (int j = 0; j < 10; j++) ssum += expf(logit[t * 10 + j] - m);
        roff[t] = m + logf(ssum);
    }
    __syncthreads();
    if (t < 80) out[t] = logit[t] - roff[t / 10];
    if (t == 0) {
        float closs = 0.f;
        closs += sq[0] * (1.0f / 12582912.0f);   // 1048576 * 1  * 12
        closs += sq[1] * (1.0f / 78643200.0f);   // 262144  * 15 * 20
        closs += sq[2] * (1.0f / 42205184.0f);   // 65536   * 23 * 28
        closs += sq[3] * (1.0f / 18284544.0f);   // 16384   * 31 * 36
        closs += sq[4] * (1.0f / 7028736.0f);    // 4096    * 39 * 44
        out[80] = closs;
    }
}

// ---------------------------------------------------------------------------

extern "C" void kernel_launch(void* const* d_in, const int* in_sizes, int n_in,
                              void* d_out, int out_size, void* d_ws, size_t ws_size,
                              hipStream_t stream)
{
    static const int NSa[6] = {65536, 16384, 4096, 1024, 256, 64};
    static const int ESa[5] = {1048576, 262144, 65536, 16384, 4096};
    static const int COa[5] = {12, 20, 28, 36, 44};
    static const int CIa[5] = {1, 15, 23, 31, 39};

    const float* x0   = (const float*)d_in[0];
    const float* pos0 = (const float*)d_in[1];

    // ---- workspace layout, 4-byte words, 256B-aligned chunks (~9.8 MB) ----
    int* wsw = (int*)d_ws;
    size_t off = 0;
    auto alw = [&](size_t n) -> size_t {
        size_t p = off; off += (n + 63) & ~(size_t)63; return p;
    };
    size_t degO[5], cdegO[5];
    for (int l = 0; l < 5; l++) degO[l]  = alw(NSa[l]);          // edge hist bins
    for (int l = 0; l < 5; l++) cdegO[l] = alw(NSa[l + 1]);      // cluster bins
    size_t HO = alw(100);                          // H[5][20] (atomic target)
    size_t zeroWords = off;                        // zero-init through here
    size_t rpO[5], crpO[5], eidO[5], cnidO[5];
    for (int l = 0; l < 5; l++) rpO[l]   = alw(NSa[l] + 1);
    for (int l = 0; l < 5; l++) crpO[l]  = alw(NSa[l + 1] + 1);
    for (int l = 0; l < 5; l++) eidO[l]  = alw(ESa[l]);
    for (int l = 0; l < 5; l++) cnidO[l] = alw(NSa[l]);
    size_t yO  = alw((size_t)65536 * 12);          // max N*CO (reused per level)
    size_t sqO = alw(8);                           // wstats output
    size_t xnO[5], pnO[5];
    for (int l = 0; l < 5; l++) xnO[l] = alw((size_t)NSa[l + 1] * (COa[l] + 3));
    for (int l = 0; l < 5; l++) pnO[l] = alw((size_t)NSa[l + 1] * 3);

    hipMemsetAsync(d_ws, 0, zeroWords * 4, stream);

    // ---- CSR builds for all 5 levels (edge-by-dst + node-by-cluster) ----
    SegArgs sa{};
    int total = 0, tiles = 0;
    for (int l = 0; l < 5; l++) {
        sa.idx[l] = (const int*)d_in[3 + 10 * l];      // dst
        sa.cnt[l] = wsw + degO[l];
        sa.rp [l] = wsw + rpO[l];
        sa.out[l] = wsw + eidO[l];
        sa.n  [l] = ESa[l];
        sa.nb [l] = NSa[l];
        sa.idx[5 + l] = (const int*)d_in[5 + 10 * l];  // cluster
        sa.cnt[5 + l] = wsw + cdegO[l];
        sa.rp [5 + l] = wsw + crpO[l];
        sa.out[5 + l] = wsw + cnidO[l];
        sa.n  [5 + l] = NSa[l];
        sa.nb [5 + l] = NSa[l + 1];
        total += ESa[l] + NSa[l];
    }
    for (int s = 0; s < 10; s++) {
        int lg = 31 - __builtin_clz(sa.nb[s]);         // log2 (nb all pow2)
        sa.shift[s] = lg - 3;                          // NBUCK = 8
        sa.tstart[s] = tiles;
        tiles += (sa.n[s] + 255) / 256;
    }
    sa.tstart[10] = tiles;

    hist_all_k   <<<(total + 255) / 256, 256, 0, stream>>>(sa, total);
    scan_all_k   <<<10, 1024, 0, stream>>>(sa);
    scatter_all_k<<<tiles * NBUCK, 256, 0, stream>>>(sa);

    // ---- h statistics + weight stats -> sq totals ----
    HArgs ha{};
    int bs = 0;
    for (int l = 0; l < 5; l++) {
        ha.eattr[l] = (const float*)d_in[4 + 10 * l];
        ha.w1[l]    = (const float*)d_in[6 + 10 * l];
        ha.b1[l]    = (const float*)d_in[7 + 10 * l];
        ha.E[l]     = ESa[l];
        ha.bstart[l] = bs;
        bs += (ESa[l] + 256 * 32 - 1) / (256 * 32);
    }
    ha.bstart[5] = bs;
    ha.H = (float*)(wsw + HO);
    hstats_k<<<bs, 256, 0, stream>>>(ha);

    WArgs wa{};
    for (int l = 0; l < 5; l++) {
        wa.w2[l]   = (const float*)d_in[8 + 10 * l];
        wa.b2[l]   = (const float*)d_in[9 + 10 * l];
        wa.cico[l] = CIa[l] * COa[l];
        wa.E[l]    = ESa[l];
    }
    wa.H  = (const float*)(wsw + HO);
    wa.sq = (float*)(wsw + sqO);
    wstats_k<<<5, 64, 0, stream>>>(wa);

    float* yb = (float*)(wsw + yO);

    // ---- level 0: thread-per-(node,group) (CI=1) ----
    node_conv_k<1, 12, 6><<<(NSa[0] * 2 + 255) / 256, 256, 0, stream>>>(
        NSa[0], wsw + rpO[0], wsw + eidO[0],
        (const int*)d_in[2], (const float*)d_in[4],
        (const float*)d_in[6], (const float*)d_in[7],
        (const float*)d_in[8], (const float*)d_in[9],
        (const float*)d_in[10], (const float*)d_in[11], x0, yb);
    pool_k<12><<<(NSa[1] * 15 + 255) / 256, 256, 0, stream>>>(
        NSa[1], wsw + crpO[0], wsw + cnidO[0], yb, pos0,
        (float*)(wsw + xnO[0]), (float*)(wsw + pnO[0]));

    // ---- levels 1-4: block-per-node cooperative ----
#define LVLC(l, CI_, CO_) do {                                                 \
    const float* xin   = (const float*)(wsw + xnO[(l) - 1]);                   \
    const float* posin = (const float*)(wsw + pnO[(l) - 1]);                   \
    int N = NSa[(l)], NN = NSa[(l) + 1];                                       \
    coop_conv_k<CI_, CO_><<<N, 256, 0, stream>>>(                              \
        wsw + rpO[(l)], wsw + eidO[(l)],                                       \
        (const int*)d_in[2 + 10 * (l)], (const float*)d_in[4 + 10 * (l)],      \
        (const float*)d_in[6 + 10 * (l)], (const float*)d_in[7 + 10 * (l)],    \
        (const float*)d_in[8 + 10 * (l)], (const float*)d_in[9 + 10 * (l)],    \
        (const float*)d_in[10 + 10 * (l)], (const float*)d_in[11 + 10 * (l)],  \
        xin, yb);                                                              \
    pool_k<CO_><<<(NN * ((CO_) + 3) + 255) / 256, 256, 0, stream>>>(           \
        NN, wsw + crpO[(l)], wsw + cnidO[(l)], yb, posin,                      \
        (float*)(wsw + xnO[(l)]), (float*)(wsw + pnO[(l)]));                   \
} while (0)

    LVLC(1, 15, 20);
    LVLC(2, 23, 28);
    LVLC(3, 31, 36);
    LVLC(4, 39, 44);
#undef LVLC

    fc_k<<<1, 128, 0, stream>>>((const float*)(wsw + xnO[4]),
                                (const float*)d_in[52], (const float*)d_in[53],
                                (const float*)(wsw + sqO), (float*)d_out);
}

// Round 7
// 545.224 us; speedup vs baseline: 3.0917x; 1.1227x over previous
//
#include <hip/hip_runtime.h>
#include <math.h>

// ---------------------------------------------------------------------------
// Net_37512244363273: 5-level edge-conditioned graph conv + voxel pooling + FC
// Round 7: round 6's top dispatch was scan_all_k (95 us, 0.26% occupancy --
// 10 blocks serially scanning 437 KB). Replaced with a 3-phase hierarchical
// scan (tile=4096: scanA per-tile sums, scanB one-wave tile-offset scan,
// scanC per-tile exclusive scan + base). Also bucketed hist_all_k by XCD
// (bucket = bin >> shift, block = bucket % 8) -- same fix that took
// scatter_all_k out of the top-5 in round 6 (device-scope atomics dirtying
// 64B lines across non-coherent XCD L2s).
// Output: [8,10] log_softmax (80) + closs = 81 floats.
// ---------------------------------------------------------------------------

#define NBUCK 8

// ---- segment descriptor for the 10 CSR builds (5 edge-dst + 5 cluster) ----
struct SegArgs {
    const int* idx[10];   // dst arrays (seg 0-4), cluster arrays (seg 5-9)
    int*       cnt[10];   // histogram (nb bins, zero-init; destroyed by scatter)
    int*       rp [10];   // exclusive scan out, nb+1 entries (rp[nb] = total)
    int*       out[10];   // CSR payload: eid / cnid (source index)
    int        n  [10];   // number of index elements (edges / nodes)
    int        nb [10];   // number of histogram bins  (nodes / clusters)
    int        shift[10]; // log2(nb) - 3 (bucket = d >> shift)
    int        tstart[11];// cumulative 256-thread tiles per segment (elements)
};

// scan auxiliaries: bin-tiles of 4096 (256 threads x 16 bins)
struct ScanAux {
    int* tilesum;         // [T]
    int* tileoff;         // [T]
    int  sstart[11];      // cumulative 4096-bin tiles per segment
    int  T;               // total bin-tiles (31 here, must be <= 64)
};

// XCD-bucketed histogram: block B -> bucket B%8 (one XCD under round-robin
// dispatch), tile B/8. Each tile is scanned by all 8 buckets; a thread
// commits its atomic only if the bin falls in this block's bucket slice ->
// all of a block's atomics land in one contiguous 1/8 range, XCD-local.
__global__ __launch_bounds__(256) void hist_all_k(SegArgs a) {
    int B = blockIdx.x;
    int bucket = B % NBUCK;
    int T = B / NBUCK;
    int s = 0;
    while (s < 9 && T >= a.tstart[s + 1]) s++;
    int i = (T - a.tstart[s]) * 256 + threadIdx.x;
    if (i >= a.n[s]) return;
    int d = a.idx[s][i];
    if ((d >> a.shift[s]) != bucket) return;
    atomicAdd(&a.cnt[s][d], 1);
}

// Phase A: per-tile totals (31 blocks, full occupancy per block).
__global__ __launch_bounds__(256) void scanA_k(SegArgs a, ScanAux x) {
    int b = blockIdx.x;
    int s = 0;
    while (s < 9 && b >= x.sstart[s + 1]) s++;
    int tloc = b - x.sstart[s];
    int nb = a.nb[s];
    const int* cnt = a.cnt[s];
    int i0 = tloc * 4096 + threadIdx.x * 16;
    int sum = 0;
    #pragma unroll
    for (int k = 0; k < 16; k++) {
        int i = i0 + k;
        if (i < nb) sum += cnt[i];
    }
    #pragma unroll
    for (int o = 32; o; o >>= 1) sum += __shfl_down(sum, o);
    __shared__ int red[4];
    if ((threadIdx.x & 63) == 0) red[threadIdx.x >> 6] = sum;
    __syncthreads();
    if (threadIdx.x == 0)
        x.tilesum[b] = red[0] + red[1] + red[2] + red[3];
}

// Phase B: one wave. shfl-scan of T<=64 tile sums; per-segment re-basing;
// writes tileoff[b] and each segment's rp[nb] total.
__global__ __launch_bounds__(64) void scanB_k(SegArgs a, ScanAux x) {
    int lane = threadIdx.x;
    int orig = (lane < x.T) ? x.tilesum[lane] : 0;
    int val = orig;
    #pragma unroll
    for (int d = 1; d < 64; d <<= 1) {
        int v = __shfl_up(val, d);
        if (lane >= d) val += v;
    }
    int excl = val - orig;                 // exclusive scan over all tiles
    int s = 0;
    while (s < 9 && lane >= x.sstart[s + 1]) s++;
    int segExcl = __shfl(excl, x.sstart[s]);
    if (lane < x.T) {
        x.tileoff[lane] = excl - segExcl;
        if (lane == x.sstart[s + 1] - 1)   // last tile of segment
            a.rp[s][a.nb[s]] = val - segExcl;
    }
}

// Phase C: per-tile exclusive scan (16 bins/thread in registers + 256-wide
// LDS scan), offset by tileoff -> final rowptr.
__global__ __launch_bounds__(256) void scanC_k(SegArgs a, ScanAux x) {
    int b = blockIdx.x;
    int s = 0;
    while (s < 9 && b >= x.sstart[s + 1]) s++;
    int tloc = b - x.sstart[s];
    int nb = a.nb[s];
    const int* cnt = a.cnt[s];
    int* rp = a.rp[s];
    int i0 = tloc * 4096 + threadIdx.x * 16;
    int v[16];
    int sum = 0;
    #pragma unroll
    for (int k = 0; k < 16; k++) {
        int i = i0 + k;
        v[k] = (i < nb) ? cnt[i] : 0;
        sum += v[k];
    }
    __shared__ int sc[256];
    int acc = sum;
    sc[threadIdx.x] = acc;
    __syncthreads();
    for (int d = 1; d < 256; d <<= 1) {
        int t2 = (threadIdx.x >= d) ? sc[threadIdx.x - d] : 0;
        __syncthreads();
        acc += t2;
        sc[threadIdx.x] = acc;
        __syncthreads();
    }
    int running = x.tileoff[b] + (acc - sum);
    #pragma unroll
    for (int k = 0; k < 16; k++) {
        int i = i0 + k;
        if (i < nb) rp[i] = running;
        running += v[k];
    }
}

// XCD-bucketed countdown-scatter (unchanged from round 6).
__global__ __launch_bounds__(256) void scatter_all_k(SegArgs a) {
    int B = blockIdx.x;
    int bucket = B % NBUCK;
    int T = B / NBUCK;
    int s = 0;
    while (s < 9 && T >= a.tstart[s + 1]) s++;
    int i = (T - a.tstart[s]) * 256 + threadIdx.x;
    if (i >= a.n[s]) return;
    int d = a.idx[s][i];
    if ((d >> a.shift[s]) != bucket) return;
    int p = atomicSub(&a.cnt[s][d], 1) - 1;
    a.out[s][a.rp[s][d] + p] = i;
}

// ---------------------------------------------------------------------------
// hstats_k: per-level h statistics over ALL edges:
//   H[l] = { H1[k]=sum_e h_ek (5), H2[p]=sum_e h_ek*h_ek' for k<=k' (15) }.
// ---------------------------------------------------------------------------
struct HArgs {
    const float* eattr[5];
    const float* w1[5];
    const float* b1[5];
    float*       H;        // [5][20], zero-init
    int          E[5];
    int          bstart[6];
};

__global__ __launch_bounds__(256) void hstats_k(HArgs a) {
    const int K = 32;
    int b = blockIdx.x, l = 0;
    while (l < 4 && b >= a.bstart[l + 1]) l++;
    int bloc = b - a.bstart[l];
    const float* ea = a.eattr[l];
    float w1r[15], b1r[5];
    #pragma unroll
    for (int i = 0; i < 15; i++) w1r[i] = a.w1[l][i];
    #pragma unroll
    for (int i = 0; i < 5; i++)  b1r[i] = a.b1[l][i];

    float acc[20];
    #pragma unroll
    for (int i = 0; i < 20; i++) acc[i] = 0.f;

    int base = bloc * 256 * K + threadIdx.x;
    for (int it = 0; it < K; it++) {
        int e = base + it * 256;
        if (e < a.E[l]) {
            float e0 = ea[e * 3], e1 = ea[e * 3 + 1], e2 = ea[e * 3 + 2];
            float h[5];
            #pragma unroll
            for (int k = 0; k < 5; k++)
                h[k] = tanhf(e0 * w1r[k] + e1 * w1r[5 + k] + e2 * w1r[10 + k] + b1r[k]);
            int p = 5;
            #pragma unroll
            for (int k = 0; k < 5; k++) {
                acc[k] += h[k];
                #pragma unroll
                for (int k2 = k; k2 < 5; k2++) acc[p++] += h[k] * h[k2];
            }
        }
    }
    __shared__ float red[4][20];
    int wid = threadIdx.x >> 6, lane = threadIdx.x & 63;
    #pragma unroll
    for (int v = 0; v < 20; v++) {
        float s = acc[v];
        #pragma unroll
        for (int off = 32; off; off >>= 1) s += __shfl_down(s, off);
        if (lane == 0) red[wid][v] = s;
    }
    __syncthreads();
    if (threadIdx.x < 20) {
        float s = red[0][threadIdx.x] + red[1][threadIdx.x] +
                  red[2][threadIdx.x] + red[3][threadIdx.x];
        atomicAdd(&a.H[l * 20 + threadIdx.x], s);
    }
}

// ---------------------------------------------------------------------------
// wstats_k: one wave per level. Contracts 21 weight dot-products with H.
// ---------------------------------------------------------------------------
struct WArgs {
    const float* w2[5];
    const float* b2[5];
    const float* H;        // [5][20]
    float*       sq;       // [5] out (raw totals)
    int          cico[5];
    int          E[5];
};

__global__ __launch_bounds__(64) void wstats_k(WArgs a) {
    int l = blockIdx.x;
    const float* w2 = a.w2[l];
    const float* b2 = a.b2[l];
    int cico = a.cico[l];
    float d[21];
    #pragma unroll
    for (int i = 0; i < 21; i++) d[i] = 0.f;
    for (int u = threadIdx.x; u < cico; u += 64) {
        float b = b2[u];
        float w[5];
        #pragma unroll
        for (int k = 0; k < 5; k++) w[k] = w2[k * cico + u];
        int p = 0;
        #pragma unroll
        for (int k = 0; k < 5; k++) {
            #pragma unroll
            for (int k2 = k; k2 < 5; k2++) d[p++] += w[k] * w[k2];
        }
        #pragma unroll
        for (int k = 0; k < 5; k++) d[15 + k] += b * w[k];
        d[20] += b * b;
    }
    #pragma unroll
    for (int i = 0; i < 21; i++) {
        #pragma unroll
        for (int off = 32; off; off >>= 1) d[i] += __shfl_down(d[i], off);
    }
    if (threadIdx.x == 0) {
        const float* H1 = a.H + l * 20;
        const float* H2 = H1 + 5;
        float sq = (float)a.E[l] * d[20];
        #pragma unroll
        for (int k = 0; k < 5; k++) sq += 2.f * d[15 + k] * H1[k];
        int p = 0;
        #pragma unroll
        for (int k = 0; k < 5; k++) {
            #pragma unroll
            for (int k2 = k; k2 < 5; k2++) {
                sq += ((k == k2) ? 1.f : 2.f) * d[p] * H2[p];
                p++;
            }
        }
        a.sq[l] = sq;
    }
}

// ---------------------------------------------------------------------------
// node_conv_k (L0 only, CI=1): thread per (node, group of OW channels).
// ---------------------------------------------------------------------------
template<int CI, int CO, int OW>
__global__ __launch_bounds__(256) void node_conv_k(
    int N,
    const int* __restrict__ rp, const int* __restrict__ eid,
    const int* __restrict__ src, const float* __restrict__ eattr,
    const float* __restrict__ w1, const float* __restrict__ b1,
    const float* __restrict__ w2, const float* __restrict__ b2,
    const float* __restrict__ root, const float* __restrict__ bias,
    const float* __restrict__ x, float* __restrict__ y)
{
    constexpr int G    = CO / OW;
    constexpr int CICO = CI * CO;
    __shared__ float w1s[15], b1s[5];
    __shared__ float w2s[5 * CICO], b2s[CICO], roots[CICO], biass[CO];
    for (int t = threadIdx.x; t < 5 * CICO; t += 256) w2s[t]   = w2[t];
    for (int t = threadIdx.x; t < CICO;     t += 256) b2s[t]   = b2[t];
    for (int t = threadIdx.x; t < CICO;     t += 256) roots[t] = root[t];
    for (int t = threadIdx.x; t < CO;       t += 256) biass[t] = bias[t];
    if (threadIdx.x < 15) w1s[threadIdx.x] = w1[threadIdx.x];
    if (threadIdx.x < 5)  b1s[threadIdx.x] = b1[threadIdx.x];
    __syncthreads();

    int t = blockIdx.x * 256 + threadIdx.x;
    if (t >= N * G) return;
    int v  = t / G;
    int ob = (t % G) * OW;
    int r0 = rp[v], r1 = rp[v + 1];
    int d  = r1 - r0;
    float acc[OW];
    #pragma unroll
    for (int oo = 0; oo < OW; oo++) acc[oo] = 0.f;

    for (int j = r0; j < r1; j++) {
        int e = eid[j];
        float ea0 = eattr[e * 3], ea1 = eattr[e * 3 + 1], ea2 = eattr[e * 3 + 2];
        float h[5];
        #pragma unroll
        for (int k = 0; k < 5; k++)
            h[k] = tanhf(ea0 * w1s[k] + ea1 * w1s[5 + k] + ea2 * w1s[10 + k] + b1s[k]);
        int sv = src[e];
        for (int i = 0; i < CI; i++) {
            float xi = x[sv * CI + i];
            #pragma unroll
            for (int oo = 0; oo < OW; oo++) {
                int o = ob + oo;
                float we = b2s[i * CO + o];
                #pragma unroll
                for (int k = 0; k < 5; k++) we += h[k] * w2s[k * CICO + i * CO + o];
                acc[oo] += xi * we;
            }
        }
    }
    float inv = 1.f / fmaxf((float)d, 1.f);
    #pragma unroll
    for (int oo = 0; oo < OW; oo++) acc[oo] *= inv;
    for (int i = 0; i < CI; i++) {
        float xi = x[v * CI + i];
        #pragma unroll
        for (int oo = 0; oo < OW; oo++)
            acc[oo] += xi * roots[i * CO + ob + oo];
    }
    #pragma unroll
    for (int oo = 0; oo < OW; oo++)
        y[(size_t)v * CO + ob + oo] = acc[oo] + biass[ob + oo];
}

// ---------------------------------------------------------------------------
// coop_conv_k (L1-L4): one block (256 threads) per node v. Factored conv.
// ---------------------------------------------------------------------------
template<int CI, int CO>
__global__ __launch_bounds__(256) void coop_conv_k(
    const int* __restrict__ rp, const int* __restrict__ eid,
    const int* __restrict__ src, const float* __restrict__ eattr,
    const float* __restrict__ w1, const float* __restrict__ b1,
    const float* __restrict__ w2, const float* __restrict__ b2,
    const float* __restrict__ root, const float* __restrict__ bias,
    const float* __restrict__ x, float* __restrict__ y)
{
    constexpr int CH   = 48;               // edges per chunk (CH*5 <= 240)
    constexpr int CICO = CI * CO;
    static_assert(6 * CI <= 256, "phase-A lanes");
    __shared__ float w1s[20];
    __shared__ int   eb[CH], svb[CH];
    __shared__ float hb[CH * 6];           // [j][k6], k6=0 -> 1.0
    __shared__ float xs[CH * CI];          // [j][i]
    __shared__ float S[6 * CI];            // [i*6 + k6]

    int t = threadIdx.x;
    int v = blockIdx.x;
    if (t < 20) w1s[t] = (t < 15) ? w1[t] : b1[t - 15];
    int r0 = rp[v], r1 = rp[v + 1];
    int d  = r1 - r0;
    float acc = 0.f;                       // this thread's (i,k6) accumulator

    for (int c0 = r0; c0 < r1; c0 += CH) {
        int cn = min(CH, r1 - c0);
        if (t < cn) {
            int e = eid[c0 + t];
            eb[t]  = e;
            svb[t] = src[e];
            hb[t * 6] = 1.f;
        }
        __syncthreads();                   // eb/svb ready (also w1s, 1st iter)
        if (t < cn * 5) {
            int j = t / 5, k = t % 5;
            int e = eb[j];
            float e0 = eattr[e * 3], e1 = eattr[e * 3 + 1], e2 = eattr[e * 3 + 2];
            hb[j * 6 + 1 + k] =
                tanhf(e0 * w1s[k] + e1 * w1s[5 + k] + e2 * w1s[10 + k] + w1s[15 + k]);
        }
        for (int u = t; u < cn * CI; u += 256)
            xs[u] = x[(size_t)svb[u / CI] * CI + (u % CI)];
        __syncthreads();                   // hb/xs ready
        if (t < 6 * CI) {
            int i = t / 6, k6 = t % 6;
            for (int j = 0; j < cn; j++)
                acc += hb[j * 6 + k6] * xs[j * CI + i];
        }
        __syncthreads();                   // protect hb/xs before next chunk
    }

    if (t < 6 * CI) S[t] = acc;
    __syncthreads();

    if (t < CO) {
        float m = 0.f;
        for (int i = 0; i < CI; i++) {
            m += b2[i * CO + t] * S[i * 6];
            #pragma unroll
            for (int k = 0; k < 5; k++)
                m += w2[k * CICO + i * CO + t] * S[i * 6 + 1 + k];
        }
        m /= fmaxf((float)d, 1.f);
        for (int i = 0; i < CI; i++)
            m += x[(size_t)v * CI + i] * root[i * CO + t];
        y[(size_t)v * CO + t] = m + bias[t];
    }
}

// ---------------------------------------------------------------------------
// pool_k: one thread per (cluster, channel). Gather-max / gather-mean.
// ---------------------------------------------------------------------------
template<int CO>
__global__ __launch_bounds__(256) void pool_k(
    int NN,
    const int* __restrict__ crp, const int* __restrict__ cnid,
    const float* __restrict__ y, const float* __restrict__ pos,
    float* __restrict__ xn,                // [NN, CO+3]
    float* __restrict__ pn)                // [NN, 3]
{
    int t = blockIdx.x * 256 + threadIdx.x;
    if (t >= NN * (CO + 3)) return;
    int c = t / (CO + 3), o = t % (CO + 3);
    int r0 = crp[c], r1 = crp[c + 1];
    int d = r1 - r0;
    if (o < CO) {
        float m = -INFINITY;
        for (int j = r0; j < r1; j++)
            m = fmaxf(m, y[(size_t)cnid[j] * CO + o]);
        if (d == 0 || !isfinite(m)) m = 0.f;
        xn[c * (CO + 3) + o] = m;
    } else {
        int k = o - CO;
        float sum = 0.f;
        for (int j = r0; j < r1; j++)
            sum += pos[cnid[j] * 3 + k];
        float pm = sum / fmaxf((float)d, 1.f);
        xn[c * (CO + 3) + CO + k] = pm;
        pn[c * 3 + k] = pm;
    }
}

// ---------------------------------------------------------------------------
// fc_k: single block. logits = feat@fc_w + fc_b; log_softmax; closs.
// ---------------------------------------------------------------------------
__global__ __launch_bounds__(128) void fc_k(
    const float* __restrict__ x5,          // [64,47] == [8,376]
    const float* __restrict__ fc_w, const float* __restrict__ fc_b,
    const float* __restrict__ sq, float* __restrict__ out)
{
    __shared__ float feat[8 * 376];
    __shared__ float logit[80];
    __shared__ float roff[8];
    for (int t = threadIdx.x; t < 8 * 376; t += 128) feat[t] = x5[t];
    __syncthreads();
    int t = threadIdx.x;
    if (t < 80) {
        int b = t / 10, j = t % 10;
        float acc = fc_b[j];
        for (int k = 0; k < 376; k++) acc += feat[b * 376 + k] * fc_w[k * 10 + j];
        logit[t] = acc;
    }
    __syncthreads();
    if (t < 8) {
        float m = -1e30f;
        for (int j = 0; j < 10; j++) m = fmaxf(m, logit[t * 10 + j]);
        float ssum = 0.f;
        for (int j = 0; j < 10; j++) ssum += expf(logit[t * 10 + j] - m);
        roff[t] = m + logf(ssum);
    }
    __syncthreads();
    if (t < 80) out[t] = logit[t] - roff[t / 10];
    if (t == 0) {
        float closs = 0.f;
        closs += sq[0] * (1.0f / 12582912.0f);   // 1048576 * 1  * 12
        closs += sq[1] * (1.0f / 78643200.0f);   // 262144  * 15 * 20
        closs += sq[2] * (1.0f / 42205184.0f);   // 65536   * 23 * 28
        closs += sq[3] * (1.0f / 18284544.0f);   // 16384   * 31 * 36
        closs += sq[4] * (1.0f / 7028736.0f);    // 4096    * 39 * 44
        out[80] = closs;
    }
}

// ---------------------------------------------------------------------------

extern "C" void kernel_launch(void* const* d_in, const int* in_sizes, int n_in,
                              void* d_out, int out_size, void* d_ws, size_t ws_size,
                              hipStream_t stream)
{
    static const int NSa[6] = {65536, 16384, 4096, 1024, 256, 64};
    static const int ESa[5] = {1048576, 262144, 65536, 16384, 4096};
    static const int COa[5] = {12, 20, 28, 36, 44};
    static const int CIa[5] = {1, 15, 23, 31, 39};

    const float* x0   = (const float*)d_in[0];
    const float* pos0 = (const float*)d_in[1];

    // ---- workspace layout, 4-byte words, 256B-aligned chunks (~9.8 MB) ----
    int* wsw = (int*)d_ws;
    size_t off = 0;
    auto alw = [&](size_t n) -> size_t {
        size_t p = off; off += (n + 63) & ~(size_t)63; return p;
    };
    size_t degO[5], cdegO[5];
    for (int l = 0; l < 5; l++) degO[l]  = alw(NSa[l]);          // edge hist bins
    for (int l = 0; l < 5; l++) cdegO[l] = alw(NSa[l + 1]);      // cluster bins
    size_t HO = alw(100);                          // H[5][20] (atomic target)
    size_t zeroWords = off;                        // zero-init through here
    size_t rpO[5], crpO[5], eidO[5], cnidO[5];
    for (int l = 0; l < 5; l++) rpO[l]   = alw(NSa[l] + 1);
    for (int l = 0; l < 5; l++) crpO[l]  = alw(NSa[l + 1] + 1);
    for (int l = 0; l < 5; l++) eidO[l]  = alw(ESa[l]);
    for (int l = 0; l < 5; l++) cnidO[l] = alw(NSa[l]);
    size_t tsO = alw(64);                          // scan tile sums
    size_t toO = alw(64);                          // scan tile offsets
    size_t yO  = alw((size_t)65536 * 12);          // max N*CO (reused per level)
    size_t sqO = alw(8);                           // wstats output
    size_t xnO[5], pnO[5];
    for (int l = 0; l < 5; l++) xnO[l] = alw((size_t)NSa[l + 1] * (COa[l] + 3));
    for (int l = 0; l < 5; l++) pnO[l] = alw((size_t)NSa[l + 1] * 3);

    hipMemsetAsync(d_ws, 0, zeroWords * 4, stream);

    // ---- CSR builds for all 5 levels (edge-by-dst + node-by-cluster) ----
    SegArgs sa{};
    int tiles = 0;
    for (int l = 0; l < 5; l++) {
        sa.idx[l] = (const int*)d_in[3 + 10 * l];      // dst
        sa.cnt[l] = wsw + degO[l];
        sa.rp [l] = wsw + rpO[l];
        sa.out[l] = wsw + eidO[l];
        sa.n  [l] = ESa[l];
        sa.nb [l] = NSa[l];
        sa.idx[5 + l] = (const int*)d_in[5 + 10 * l];  // cluster
        sa.cnt[5 + l] = wsw + cdegO[l];
        sa.rp [5 + l] = wsw + crpO[l];
        sa.out[5 + l] = wsw + cnidO[l];
        sa.n  [5 + l] = NSa[l];
        sa.nb [5 + l] = NSa[l + 1];
    }
    ScanAux sx{};
    int btiles = 0;
    for (int s = 0; s < 10; s++) {
        int lg = 31 - __builtin_clz(sa.nb[s]);         // log2 (nb all pow2)
        sa.shift[s] = lg - 3;                          // NBUCK = 8
        sa.tstart[s] = tiles;
        tiles += (sa.n[s] + 255) / 256;
        sx.sstart[s] = btiles;
        btiles += (sa.nb[s] + 4095) / 4096;
    }
    sa.tstart[10] = tiles;
    sx.sstart[10] = btiles;
    sx.T = btiles;                                     // 31 <= 64
    sx.tilesum = wsw + tsO;
    sx.tileoff = wsw + toO;

    hist_all_k   <<<tiles * NBUCK, 256, 0, stream>>>(sa);
    scanA_k      <<<btiles, 256, 0, stream>>>(sa, sx);
    scanB_k      <<<1, 64, 0, stream>>>(sa, sx);
    scanC_k      <<<btiles, 256, 0, stream>>>(sa, sx);
    scatter_all_k<<<tiles * NBUCK, 256, 0, stream>>>(sa);

    // ---- h statistics + weight stats -> sq totals ----
    HArgs ha{};
    int bs = 0;
    for (int l = 0; l < 5; l++) {
        ha.eattr[l] = (const float*)d_in[4 + 10 * l];
        ha.w1[l]    = (const float*)d_in[6 + 10 * l];
        ha.b1[l]    = (const float*)d_in[7 + 10 * l];
        ha.E[l]     = ESa[l];
        ha.bstart[l] = bs;
        bs += (ESa[l] + 256 * 32 - 1) / (256 * 32);
    }
    ha.bstart[5] = bs;
    ha.H = (float*)(wsw + HO);
    hstats_k<<<bs, 256, 0, stream>>>(ha);

    WArgs wa{};
    for (int l = 0; l < 5; l++) {
        wa.w2[l]   = (const float*)d_in[8 + 10 * l];
        wa.b2[l]   = (const float*)d_in[9 + 10 * l];
        wa.cico[l] = CIa[l] * COa[l];
        wa.E[l]    = ESa[l];
    }
    wa.H  = (const float*)(wsw + HO);
    wa.sq = (float*)(wsw + sqO);
    wstats_k<<<5, 64, 0, stream>>>(wa);

    float* yb = (float*)(wsw + yO);

    // ---- level 0: thread-per-(node,group) (CI=1) ----
    node_conv_k<1, 12, 6><<<(NSa[0] * 2 + 255) / 256, 256, 0, stream>>>(
        NSa[0], wsw + rpO[0], wsw + eidO[0],
        (const int*)d_in[2], (const float*)d_in[4],
        (const float*)d_in[6], (const float*)d_in[7],
        (const float*)d_in[8], (const float*)d_in[9],
        (const float*)d_in[10], (const float*)d_in[11], x0, yb);
    pool_k<12><<<(NSa[1] * 15 + 255) / 256, 256, 0, stream>>>(
        NSa[1], wsw + crpO[0], wsw + cnidO[0], yb, pos0,
        (float*)(wsw + xnO[0]), (float*)(wsw + pnO[0]));

    // ---- levels 1-4: block-per-node cooperative ----
#define LVLC(l, CI_, CO_) do {                                                 \
    const float* xin   = (const float*)(wsw + xnO[(l) - 1]);                   \
    const float* posin = (const float*)(wsw + pnO[(l) - 1]);                   \
    int N = NSa[(l)], NN = NSa[(l) + 1];                                       \
    coop_conv_k<CI_, CO_><<<N, 256, 0, stream>>>(                              \
        wsw + rpO[(l)], wsw + eidO[(l)],                                       \
        (const int*)d_in[2 + 10 * (l)], (const float*)d_in[4 + 10 * (l)],      \
        (const float*)d_in[6 + 10 * (l)], (const float*)d_in[7 + 10 * (l)],    \
        (const float*)d_in[8 + 10 * (l)], (const float*)d_in[9 + 10 * (l)],    \
        (const float*)d_in[10 + 10 * (l)], (const float*)d_in[11 + 10 * (l)],  \
        xin, yb);                                                              \
    pool_k<CO_><<<(NN * ((CO_) + 3) + 255) / 256, 256, 0, stream>>>(           \
        NN, wsw + crpO[(l)], wsw + cnidO[(l)], yb, posin,                      \
        (float*)(wsw + xnO[(l)]), (float*)(wsw + pnO[(l)]));                   \
} while (0)

    LVLC(1, 15, 20);
    LVLC(2, 23, 28);
    LVLC(3, 31, 36);
    LVLC(4, 39, 44);
#undef LVLC

    fc_k<<<1, 128, 0, stream>>>((const float*)(wsw + xnO[4]),
                                (const float*)d_in[52], (const float*)d_in[53],
                                (const float*)(wsw + sqO), (float*)d_out);
}